// Round 9
// baseline (179.951 us; speedup 1.0000x reference)
//
#include <hip/hip_runtime.h>
#include <math.h>

#define LL 1024
#define DD 768
#define HH 12
#define CL 16
#define NC 64   // LL / CL
#define NBH 24  // B*H

typedef __bf16 bf16x8 __attribute__((ext_vector_type(8)));
typedef __bf16 bf16x4 __attribute__((ext_vector_type(4)));
typedef float floatx4 __attribute__((ext_vector_type(4)));

typedef const void __attribute__((address_space(1)))* gas_ptr;
typedef void __attribute__((address_space(3)))* las_ptr;

__device__ __forceinline__ void gl_lds16(const void* g, void* s) {
  __builtin_amdgcn_global_load_lds((gas_ptr)g, (las_ptr)s, 16, 0, 0);
}

__device__ __forceinline__ float wave_sum64(float v) {
#pragma unroll
  for (int off = 32; off; off >>= 1) v += __shfl_xor(v, off, 64);
  return v;
}

__device__ __forceinline__ float sigm(float x) { return 1.0f / (1.0f + expf(-x)); }
__device__ __forceinline__ float clamp5(float x) {
  return __builtin_amdgcn_fmed3f(x, -5.f, 5.f);
}

// ---------------- K1: prep — fused weight converts + conv+LN ----------------
__global__ __launch_bounds__(256) void prep_kernel(
    const float* __restrict__ x, const float* __restrict__ cw,
    const float* __restrict__ cb, const float* __restrict__ g,
    const float* __restrict__ bta, __bf16* __restrict__ xn,
    const float* __restrict__ qkvw, const float* __restrict__ bnw1,
    const float* __restrict__ projw, const float* __restrict__ w2,
    __bf16* __restrict__ wqb, __bf16* __restrict__ dp, __bf16* __restrict__ dw2) {
  if (blockIdx.x >= 2048) {             // ---- convert path ----
    int i = (blockIdx.x - 2048) * 256 + threadIdx.x;
    if (i >= 647168) return;
    bf16x4 o;
    if (i >= 638976) {                  // w2 pad region (128x256 bf16)
      int off = i - 638976;
      if (off < 3840) {
        float4 v = ((const float4*)w2)[off];
        o[0] = (__bf16)v.x; o[1] = (__bf16)v.y; o[2] = (__bf16)v.z; o[3] = (__bf16)v.w;
      } else {
        o[0] = (__bf16)0.f; o[1] = (__bf16)0.f; o[2] = (__bf16)0.f; o[3] = (__bf16)0.f;
      }
      ((bf16x4*)dw2)[off] = o;
      return;
    }
    const float* s; __bf16* d; int off;
    if (i < 442368)      { s = qkvw;  d = wqb;  off = i; }
    else if (i < 491520) { s = bnw1;  d = wqb;  off = i; }      // contiguous concat
    else                 { s = projw; d = dp;   off = i - 491520; }
    int soff = (i < 442368) ? i : (i < 491520 ? i - 442368 : off);
    float4 v = ((const float4*)s)[soff];
    o[0] = (__bf16)v.x; o[1] = (__bf16)v.y; o[2] = (__bf16)v.z; o[3] = (__bf16)v.w;
    ((bf16x4*)d)[off] = o;
    return;
  }
  // ---- conv + LN path ----
  int row = blockIdx.x;            // b*L + l
  int l = row & (LL - 1);
  const float* xr = x + (size_t)row * DD;
  __shared__ float red[16];
  float vals[3];
  float s = 0.f, ss = 0.f;
#pragma unroll
  for (int i = 0; i < 3; i++) {
    int d = threadIdx.x + i * 256;
    float x0 = xr[d];
    float xm1 = (l >= 1) ? xr[d - DD] : 0.f;
    float xm2 = (l >= 2) ? xr[d - 2 * DD] : 0.f;
    float c = xm2 * cw[d * 3 + 0] + xm1 * cw[d * 3 + 1] + x0 * cw[d * 3 + 2] + cb[d];
    float v = x0 + c;
    vals[i] = v; s += v; ss += v * v;
  }
  s = wave_sum64(s); ss = wave_sum64(ss);
  int wid = threadIdx.x >> 6;
  if ((threadIdx.x & 63) == 0) { red[wid * 2] = s; red[wid * 2 + 1] = ss; }
  __syncthreads();
  if (threadIdx.x == 0) {
    red[8] = red[0] + red[2] + red[4] + red[6];
    red[9] = red[1] + red[3] + red[5] + red[7];
  }
  __syncthreads();
  float mu = red[8] * (1.f / 768.f);
  float var = red[9] * (1.f / 768.f) - mu * mu;
  float inv = rsqrtf(var + 1e-5f);
  __bf16* xo = xn + (size_t)row * DD;
#pragma unroll
  for (int i = 0; i < 3; i++) {
    int d = threadIdx.x + i * 256;
    xo[d] = (__bf16)((vals[i] - mu) * inv * g[d] + bta[d]);
  }
}

// ---------------- K2: bf16 MFMA GEMM  C = A(M,K) * B(N,K)^T + bias ----------
// 1-D grid with XCD swizzle: id&7 picks M-stripe group (NY/8 y-tiles each) so
// each XCD's L2 keeps one A-stripe + B. BM x 128 tile, BK=64, gl_lds staging.
// MODE 0: plain out; MODE 3: fused qkv+bn epilogue (q/k elu+1 -> bf16 qkva,
//   v -> bf16 qkva, silu -> bf16 hbuf)
template <int BM, int NY, int MODE, bool HASBIAS, bool OUTBF>
__global__ __launch_bounds__(256) void gemm_mfma_kernel(
    const __bf16* __restrict__ A, const __bf16* __restrict__ Bw,
    const float* __restrict__ bias, void* __restrict__ Cv, void* __restrict__ C2,
    int M, int N, int K) {
  constexpr int MI = BM / 32;
  constexpr int NYG = NY / 8;
  __shared__ __attribute__((aligned(16))) __bf16 As[BM * 64];
  __shared__ __attribute__((aligned(16))) __bf16 Bs[128 * 64];
  int id = blockIdx.x;
  int by = (id & 7) * NYG + ((id >> 3) % NYG);
  int bx = (id >> 3) / NYG;
  int m0 = by * BM, n0 = bx * 128;
  int tid = threadIdx.x;
  int w = tid >> 6, lane = tid & 63;
  int wm = w >> 1, wn = w & 1;
  int quad = lane >> 4, l16 = lane & 15;

  int lrow = lane >> 3;
  int lchunk = (lane & 7) ^ lrow;
  int R0 = w * 8;

  floatx4 acc[MI][4];
#pragma unroll
  for (int i = 0; i < MI; i++)
#pragma unroll
    for (int j = 0; j < 4; j++) acc[i][j] = (floatx4)0.f;

  for (int k0 = 0; k0 < K; k0 += 64) {
    __syncthreads();
#pragma unroll
    for (int r = 0; r < BM / 32; r++) {
      int row = r * 32 + R0 + lrow;
      gl_lds16(A + (size_t)(m0 + row) * K + k0 + lchunk * 8, &As[(r * 32 + R0) * 64]);
    }
#pragma unroll
    for (int r = 0; r < 4; r++) {
      int row = r * 32 + R0 + lrow;
      gl_lds16(Bw + (size_t)(n0 + row) * K + k0 + lchunk * 8, &Bs[(r * 32 + R0) * 64]);
    }
    __syncthreads();
#pragma unroll
    for (int s = 0; s < 2; s++) {
      bf16x8 af[MI], bfr[4];
      int csw = (s << 2) + quad;
#pragma unroll
      for (int i = 0; i < MI; i++) {
        int m = wm * (BM / 2) + i * 16 + l16;
        af[i] = *(const bf16x8*)&As[m * 64 + (csw ^ (l16 & 7)) * 8];
      }
#pragma unroll
      for (int j = 0; j < 4; j++) {
        int n = wn * 64 + j * 16 + l16;
        bfr[j] = *(const bf16x8*)&Bs[n * 64 + (csw ^ (l16 & 7)) * 8];
      }
#pragma unroll
      for (int i = 0; i < MI; i++)
#pragma unroll
        for (int j = 0; j < 4; j++)
          acc[i][j] = __builtin_amdgcn_mfma_f32_16x16x32_bf16(af[i], bfr[j], acc[i][j], 0, 0, 0);
    }
  }
#pragma unroll
  for (int j = 0; j < 4; j++) {
    int gcol = n0 + wn * 64 + j * 16 + l16;
    if (MODE == 3) {
      if (gcol < 2304) {
        float bv = bias[gcol];
        bool isqk = gcol < 1536;
#pragma unroll
        for (int i = 0; i < MI; i++) {
          int grow = m0 + wm * (BM / 2) + i * 16 + quad * 4;
#pragma unroll
          for (int r = 0; r < 4; r++) {
            float v = acc[i][j][r] + bv;
            if (isqk) v = (v > 0.f) ? v + 1.f : expf(v);
            ((__bf16*)Cv)[(size_t)(grow + r) * 2304 + gcol] = (__bf16)v;
          }
        }
      } else {
        int hcol = gcol - 2304;
#pragma unroll
        for (int i = 0; i < MI; i++) {
          int grow = m0 + wm * (BM / 2) + i * 16 + quad * 4;
#pragma unroll
          for (int r = 0; r < 4; r++) {
            float v = acc[i][j][r];
            v = v / (1.f + expf(-v));
            ((__bf16*)C2)[(size_t)(grow + r) * 256 + hcol] = (__bf16)v;
          }
        }
      }
    } else {
      float bv = HASBIAS ? bias[gcol] : 0.f;
#pragma unroll
      for (int i = 0; i < MI; i++) {
        int grow = m0 + wm * (BM / 2) + i * 16 + quad * 4;
#pragma unroll
        for (int r = 0; r < 4; r++) {
          float v = acc[i][j][r] + bv;
          if (OUTBF) ((__bf16*)Cv)[(size_t)(grow + r) * N + gcol] = (__bf16)v;
          else       ((float*)Cv)[(size_t)(grow + r) * N + gcol] = v;
        }
      }
    }
  }
}

// ---------------- K3: params transform + df (fused, one block per bh) -------
__global__ __launch_bounds__(256) void params_df_kernel(
    const float* __restrict__ pp, const float* __restrict__ temp,
    float* __restrict__ gate, float* __restrict__ dec, float* __restrict__ dfb) {
  int bh = blockIdx.x;             // < 24
  int b = bh / HH, h = bh - b * HH;
  int tid = threadIdx.x;
  int lane = tid & 63, wid = tid >> 6;
  float tv = temp[0];
  const float PI = 3.14159265358979323846f;
  double ls[4];
  double lsum = 0.0;
#pragma unroll
  for (int i = 0; i < 4; i++) {
    int l = tid * 4 + i;
    int row = (b << 10) + l;
    const float* p = pp + (size_t)row * 128 + h * 5;
    float p0 = p[0], p1 = p[1], p2 = p[2], p3 = p[3], p4 = p[4];
    float sa = sigm(p0);
    float sp = tanhf(p1) * PI;
    float ca = sigm(p2);
    float cp = tanhf(p3) * PI;
    float dc = 0.3f + 0.65f * sigm(p4);
    float gt = sigm(sa * ca * cosf(sp - cp) * tv);
    gate[row * HH + h] = gt;
    dec[(bh << 10) + l] = dc;
    lsum += (double)logf(dc);
    ls[i] = lsum;
  }
  double run = lsum;
#pragma unroll
  for (int off = 1; off < 64; off <<= 1) {
    double n = __shfl_up(run, off, 64);
    if (lane >= off) run += n;
  }
  __shared__ double wsum[4];
  if (lane == 63) wsum[wid] = run;
  __syncthreads();
  double wexcl = 0.0;
  for (int k = 0; k < wid; k++) wexcl += wsum[k];
  double excl = wexcl + run - lsum;
  float* dfo = dfb + (bh << 10) + tid * 4;
#pragma unroll
  for (int i = 0; i < 4; i++) dfo[i] = expf((float)(excl + ls[i]));
}

// ---------------- K5: scan phase1 — d-split, bf16 qkva, full residency ------
__global__ __launch_bounds__(256, 6) void scan_phase1(
    const __bf16* __restrict__ qkv, const float* __restrict__ dec,
    const float* __restrict__ df, const float* __restrict__ gate,
    __bf16* __restrict__ kvcs, float* __restrict__ zcs, float* __restrict__ Aarr) {
  int blk = blockIdx.x;            // bh*NC + c
  int bh = blk >> 6, c = blk & (NC - 1);
  int b = bh / HH, h = bh - b * HH;
  int tid = threadIdx.x;
  int w = tid >> 6, e = tid & 63;
  int t0 = c * CL;
  __shared__ __attribute__((aligned(16))) __bf16 kbuf[CL][64];
  __shared__ __attribute__((aligned(16))) __bf16 vbuf[CL][64];
  __shared__ float sbuf[CL][4];
  // staging: w0: k rows0-7, w1: k rows8-15, w2: v rows0-7, w3: v rows8-15
  {
    int trow = ((w & 1) << 3) + (e >> 3);
    int chunk = e & 7;
    int sec = (w < 2) ? 1 : 2;
    const __bf16* gp = qkv + ((size_t)(b * LL + t0 + trow) * 2304 + sec * 768 + h * 64 + chunk * 8);
    void* dst = (w < 2) ? (void*)&kbuf[(w & 1) << 3][0] : (void*)&vbuf[(w & 1) << 3][0];
    gl_lds16(gp, dst);
  }
  if (tid < CL) {
    int t = t0 + tid;
    float a = dec[bh * LL + t];
    float d = df[bh * LL + t];
    float r = d / (d + 1e-8f);
    float g = gate[(b * LL + t) * HH + h];
    sbuf[tid][0] = a; sbuf[tid][1] = r; sbuf[tid][2] = g * (1.f - a);
    sbuf[tid][3] = (1.f - a) * r;
  }
  __syncthreads();
  float KV[16];
#pragma unroll
  for (int d = 0; d < 16; d++) KV[d] = 0.f;
  float z = 0.f, A = 1.f;
  for (int t = 0; t < CL; t++) {
    float a = sbuf[t][0], r = sbuf[t][1], cs = sbuf[t][2], w1r = sbuf[t][3];
    float vc = (float)vbuf[t][e] * cs;
    A *= a;
    bf16x8 k0 = *(const bf16x8*)&kbuf[t][w << 4];
    bf16x8 k1 = *(const bf16x8*)&kbuf[t][(w << 4) + 8];
#pragma unroll
    for (int j = 0; j < 8; j++) {
      float u = clamp5((float)k0[j] * vc);
      KV[j] = fmaf(a, KV[j], r * u);
    }
#pragma unroll
    for (int j = 0; j < 8; j++) {
      float u = clamp5((float)k1[j] * vc);
      KV[8 + j] = fmaf(a, KV[8 + j], r * u);
    }
    z = fmaf(a, z, (float)kbuf[t][e] * w1r);
  }
  __bf16* kvo = kvcs + (size_t)blk * 4096 + (w << 4) * 64 + e;
#pragma unroll
  for (int d = 0; d < 16; d++) kvo[d * 64] = (__bf16)KV[d];
  if (w == 0) zcs[blk * 64 + e] = z;
  if (tid == 0) Aarr[blk] = A;
}

// ---------------- K6: sequential carry combine (in-place end->init) ---------
__global__ __launch_bounds__(256) void combine_kernel(
    const float* __restrict__ Aarr, __bf16* __restrict__ kv, float* __restrict__ z) {
  int g = blockIdx.x * 256 + threadIdx.x;
  if (g < NBH * 4096) {
    int bh = g >> 12, idx = g & 4095;
    const float* Ap = Aarr + bh * NC;
    __bf16* p = kv + (size_t)bh * NC * 4096 + idx;
    float carry = 0.f;
#pragma unroll 8
    for (int c = 0; c < NC; c++) {
      float endv = (float)p[(size_t)c * 4096];
      p[(size_t)c * 4096] = (__bf16)carry;
      carry = fmaf(Ap[c], carry, endv);
    }
  } else {
    int g2 = g - NBH * 4096;
    if (g2 >= NBH * 64) return;
    int bh = g2 >> 6, idx = g2 & 63;
    const float* Ap = Aarr + bh * NC;
    float* p = z + bh * NC * 64 + idx;
    float carry = 0.f;
#pragma unroll 8
    for (int c = 0; c < NC; c++) {
      float endv = p[c * 64];
      p[c * 64] = carry;
      carry = fmaf(Ap[c], carry, endv);
    }
  }
}

// ---------------- K7: scan phase3 — half-buffered pbuf, full residency ------
__global__ __launch_bounds__(256, 6) void scan_phase3(
    const __bf16* __restrict__ qkv, const float* __restrict__ dec,
    const float* __restrict__ df, const float* __restrict__ gate,
    const __bf16* __restrict__ kvcs, const float* __restrict__ zcs,
    const float* __restrict__ mng, const float* __restrict__ mnb,
    __bf16* __restrict__ att) {
  int blk = blockIdx.x;
  int bh = blk >> 6, c = blk & (NC - 1);
  int b = bh / HH, h = bh - b * HH;
  int tid = threadIdx.x;
  int w = tid >> 6, e = tid & 63;
  int t0 = c * CL;
  __shared__ __attribute__((aligned(16))) __bf16 qbuf[CL][64];
  __shared__ __attribute__((aligned(16))) __bf16 kbuf[CL][64];
  __shared__ __attribute__((aligned(16))) __bf16 vbuf[CL][64];
  __shared__ float sbuf[CL][4];
  __shared__ float pbuf[8][4][64];   // half-buffer
  // staging: w0: q0-7 + k0-7, w1: q8-15 + k8-15, w2: v0-7, w3: v8-15
  {
    int trow = ((w & 1) << 3) + (e >> 3);
    int chunk = e & 7;
    size_t rowbase = (size_t)(b * LL + t0 + trow) * 2304 + h * 64 + chunk * 8;
    if (w < 2) {
      gl_lds16(qkv + rowbase, &qbuf[(w & 1) << 3][0]);
      gl_lds16(qkv + rowbase + 768, &kbuf[(w & 1) << 3][0]);
    } else {
      gl_lds16(qkv + rowbase + 1536, &vbuf[(w & 1) << 3][0]);
    }
  }
  if (tid < CL) {
    int t = t0 + tid;
    float a = dec[bh * LL + t];
    float d = df[bh * LL + t];
    float r = d / (d + 1e-8f);
    float g = gate[(b * LL + t) * HH + h];
    sbuf[tid][0] = a; sbuf[tid][1] = r; sbuf[tid][2] = g * (1.f - a);
    sbuf[tid][3] = (1.f - a) * r;
  }
  float KV[16];
  const __bf16* kvi = kvcs + (size_t)blk * 4096 + (w << 4) * 64 + e;
#pragma unroll
  for (int d = 0; d < 16; d++) KV[d] = (float)kvi[d * 64];
  float z = zcs[blk * 64 + e];
  float zsnap[4];
  float mg = mng[e], mb = mnb[e];
  __syncthreads();
#pragma unroll
  for (int half = 0; half < 2; half++) {
    for (int tt = 0; tt < 8; tt++) {
      int t = (half << 3) + tt;
      float a = sbuf[t][0], r = sbuf[t][1], cs = sbuf[t][2], w1r = sbuf[t][3];
      float vc = (float)vbuf[t][e] * cs;
      float onp = 0.f;
      bf16x8 k0 = *(const bf16x8*)&kbuf[t][w << 4];
      bf16x8 k1 = *(const bf16x8*)&kbuf[t][(w << 4) + 8];
      bf16x8 q0 = *(const bf16x8*)&qbuf[t][w << 4];
      bf16x8 q1 = *(const bf16x8*)&qbuf[t][(w << 4) + 8];
#pragma unroll
      for (int j = 0; j < 8; j++) {
        float u = clamp5((float)k0[j] * vc);
        float nv = fmaf(a, KV[j], r * u);
        KV[j] = nv;
        onp = fmaf((float)q0[j], nv, onp);
      }
#pragma unroll
      for (int j = 0; j < 8; j++) {
        float u = clamp5((float)k1[j] * vc);
        float nv = fmaf(a, KV[8 + j], r * u);
        KV[8 + j] = nv;
        onp = fmaf((float)q1[j], nv, onp);
      }
      pbuf[tt][w][e] = onp;
      z = fmaf(a, z, (float)kbuf[t][e] * w1r);
      if ((tt >> 1) == w) zsnap[(half << 1) | (tt & 1)] = z;
    }
    __syncthreads();
    // wave w reduces tt = 2w, 2w+1 of this half
#pragma unroll
    for (int i = 0; i < 2; i++) {
      int tt = (w << 1) + i;
      int t = (half << 3) + tt;
      float on = pbuf[tt][0][e] + pbuf[tt][1][e] + pbuf[tt][2][e] + pbuf[tt][3][e];
      float zc = __builtin_amdgcn_fmed3f(zsnap[(half << 1) | i], -10000.f, 10000.f);
      float qe = (float)qbuf[t][e];
      float s0 = qe * zc, s1 = on, s2 = on * on;
#pragma unroll
      for (int off = 32; off; off >>= 1) {
        s0 += __shfl_xor(s0, off, 64);
        s1 += __shfl_xor(s1, off, 64);
        s2 += __shfl_xor(s2, off, 64);
      }
      float den = s0 + 1e-4f;
      float idn = 1.f / den;
      float o = on * idn;
      float mu = s1 * idn * (1.f / 64.f);
      float E2 = s2 * idn * idn * (1.f / 64.f);
      float var = E2 - mu * mu;
      float outv = (o - mu) * rsqrtf(var + 1e-5f) * mg + mb;
      att[((size_t)(b * LL + t0 + t)) * DD + h * 64 + e] = (__bf16)outv;
    }
    if (half == 0) __syncthreads();
  }
}

// ---------------------------------------------------------------------------
extern "C" void kernel_launch(void* const* d_in, const int* in_sizes, int n_in,
                              void* d_out, int out_size, void* d_ws, size_t ws_size,
                              hipStream_t stream) {
  (void)in_sizes; (void)n_in; (void)out_size; (void)ws_size;
  const float* x           = (const float*)d_in[0];
  const float* conv_w      = (const float*)d_in[1];
  const float* conv_b      = (const float*)d_in[2];
  const float* ln_g        = (const float*)d_in[3];
  const float* ln_b        = (const float*)d_in[4];
  const float* qkv_w       = (const float*)d_in[5];
  const float* qkv_b       = (const float*)d_in[6];
  const float* bn_w1       = (const float*)d_in[7];
  const float* bn_w2       = (const float*)d_in[8];
  const float* temperature = (const float*)d_in[9];
  const float* proj_w      = (const float*)d_in[10];
  const float* proj_b      = (const float*)d_in[11];
  const float* mn_g        = (const float*)d_in[12];
  const float* mn_b        = (const float*)d_in[13];

  float* y    = (float*)d_out;
  float* gate = y + 2 * 1024 * 768;      // outputs concatenated: y then gate

  char* ws = (char*)d_ws;
  __bf16* xn_bf   = (__bf16*)(ws);                 // 3.15 MB, reused as att_bf
  __bf16* att_bf  = xn_bf;                         // alias (xn dead before phase3)
  __bf16* qkva    = (__bf16*)(ws + 3145728);       // 9.44 MB bf16 (q|k|v, stride 2304)
  __bf16* hbuf_bf = (__bf16*)(ws + 12582912);      // 1.05 MB (2048x256 bf16)
  float*  pp      = (float*)(ws + 13631488);       // 1.05 MB (2048x128 fp32)
  float*  dec     = (float*)(ws + 14680064);       // 96 KB  (B,H,L)
  float*  dfb     = (float*)(ws + 14778368);       // 96 KB
  __bf16* kvcs    = (__bf16*)(ws + 14876672);      // 12.58 MB bf16 (end->init in place)
  __bf16* wqb_bf  = (__bf16*)(ws + 14876672);      // 3.93 MB alias (dead before phase1)
  float*  zcs     = (float*)(ws + 27459584);       // 384 KB
  float*  Aarr    = (float*)(ws + 27852800);       // 6 KB
  __bf16* projw_bf= (__bf16*)(ws + 27858944);      // 1.18 MB
  __bf16* w2p_bf  = (__bf16*)(ws + 29038592);      // 64 KB -> total 29.1 MB

  // prep: conv+LN (blocks 0..2047) + all weight converts (blocks 2048..4575)
  prep_kernel<<<4576, 256, 0, stream>>>(x, conv_w, conv_b, ln_g, ln_b, xn_bf,
                                        qkv_w, bn_w1, proj_w, bn_w2,
                                        wqb_bf, projw_bf, w2p_bf);

  // fused qkv+bn1 -> bf16 qkva + bf16 h   (grid 640 = 20 x-tiles * 32 y-tiles)
  gemm_mfma_kernel<64, 32, 3, true, false><<<640, 256, 0, stream>>>(
      xn_bf, wqb_bf, qkv_b, qkva, hbuf_bf, 2048, 2560, 768);

  // pp = h @ w2p.T  (grid 32 = 1 x-tile * 32 y-tiles)
  gemm_mfma_kernel<64, 32, 0, false, false><<<32, 256, 0, stream>>>(
      hbuf_bf, w2p_bf, nullptr, pp, nullptr, 2048, 128, 256);

  params_df_kernel<<<NBH, 256, 0, stream>>>(pp, temperature, gate, dec, dfb);

  scan_phase1<<<NBH * NC, 256, 0, stream>>>(qkva, dec, dfb, gate, kvcs, zcs, Aarr);

  combine_kernel<<<390, 256, 0, stream>>>(Aarr, kvcs, zcs);

  scan_phase3<<<NBH * NC, 256, 0, stream>>>(qkva, dec, dfb, gate, kvcs, zcs,
                                            mn_g, mn_b, att_bf);

  // y = att @ proj_w.T + proj_b   (grid 192 = 6 x-tiles * 32 y-tiles)
  gemm_mfma_kernel<64, 32, 0, true, false><<<192, 256, 0, stream>>>(
      att_bf, projw_bf, proj_b, y, nullptr, 2048, 768, 768);
}

// Round 11
// 173.947 us; speedup vs baseline: 1.0345x; 1.0345x over previous
//
#include <hip/hip_runtime.h>
#include <math.h>

#define LL 1024
#define DD 768
#define HH 12
#define CL 16
#define NC 64   // LL / CL
#define NBH 24  // B*H

typedef __bf16 bf16x8 __attribute__((ext_vector_type(8)));
typedef __bf16 bf16x4 __attribute__((ext_vector_type(4)));
typedef float floatx4 __attribute__((ext_vector_type(4)));

typedef const void __attribute__((address_space(1)))* gas_ptr;
typedef void __attribute__((address_space(3)))* las_ptr;

__device__ __forceinline__ void gl_lds16(const void* g, void* s) {
  __builtin_amdgcn_global_load_lds((gas_ptr)g, (las_ptr)s, 16, 0, 0);
}

__device__ __forceinline__ float wave_sum64(float v) {
#pragma unroll
  for (int off = 32; off; off >>= 1) v += __shfl_xor(v, off, 64);
  return v;
}

__device__ __forceinline__ float sigm(float x) { return 1.0f / (1.0f + expf(-x)); }
__device__ __forceinline__ float clamp5(float x) {
  return __builtin_amdgcn_fmed3f(x, -5.f, 5.f);
}

// ---------------- K1: prep — fused weight converts + conv+LN ----------------
__global__ __launch_bounds__(256) void prep_kernel(
    const float* __restrict__ x, const float* __restrict__ cw,
    const float* __restrict__ cb, const float* __restrict__ g,
    const float* __restrict__ bta, __bf16* __restrict__ xn,
    const float* __restrict__ qkvw, const float* __restrict__ bnw1,
    const float* __restrict__ projw, const float* __restrict__ w2,
    __bf16* __restrict__ wqb, __bf16* __restrict__ dp, __bf16* __restrict__ dw2) {
  if (blockIdx.x >= 2048) {             // ---- convert path ----
    int i = (blockIdx.x - 2048) * 256 + threadIdx.x;
    if (i >= 647168) return;
    bf16x4 o;
    if (i >= 638976) {                  // w2 pad region (128x256 bf16)
      int off = i - 638976;
      if (off < 3840) {
        float4 v = ((const float4*)w2)[off];
        o[0] = (__bf16)v.x; o[1] = (__bf16)v.y; o[2] = (__bf16)v.z; o[3] = (__bf16)v.w;
      } else {
        o[0] = (__bf16)0.f; o[1] = (__bf16)0.f; o[2] = (__bf16)0.f; o[3] = (__bf16)0.f;
      }
      ((bf16x4*)dw2)[off] = o;
      return;
    }
    const float* s; __bf16* d; int off, soff;
    if (i < 442368)      { s = qkvw;  d = wqb; off = i; soff = i; }
    else if (i < 491520) { s = bnw1;  d = wqb; off = i; soff = i - 442368; }
    else                 { s = projw; d = dp;  off = i - 491520; soff = off; }
    float4 v = ((const float4*)s)[soff];
    o[0] = (__bf16)v.x; o[1] = (__bf16)v.y; o[2] = (__bf16)v.z; o[3] = (__bf16)v.w;
    ((bf16x4*)d)[off] = o;
    return;
  }
  // ---- conv + LN path ----
  int row = blockIdx.x;            // b*L + l
  int l = row & (LL - 1);
  const float* xr = x + (size_t)row * DD;
  __shared__ float red[16];
  float vals[3];
  float s = 0.f, ss = 0.f;
#pragma unroll
  for (int i = 0; i < 3; i++) {
    int d = threadIdx.x + i * 256;
    float x0 = xr[d];
    float xm1 = (l >= 1) ? xr[d - DD] : 0.f;
    float xm2 = (l >= 2) ? xr[d - 2 * DD] : 0.f;
    float c = xm2 * cw[d * 3 + 0] + xm1 * cw[d * 3 + 1] + x0 * cw[d * 3 + 2] + cb[d];
    float v = x0 + c;
    vals[i] = v; s += v; ss += v * v;
  }
  s = wave_sum64(s); ss = wave_sum64(ss);
  int wid = threadIdx.x >> 6;
  if ((threadIdx.x & 63) == 0) { red[wid * 2] = s; red[wid * 2 + 1] = ss; }
  __syncthreads();
  if (threadIdx.x == 0) {
    red[8] = red[0] + red[2] + red[4] + red[6];
    red[9] = red[1] + red[3] + red[5] + red[7];
  }
  __syncthreads();
  float mu = red[8] * (1.f / 768.f);
  float var = red[9] * (1.f / 768.f) - mu * mu;
  float inv = rsqrtf(var + 1e-5f);
  __bf16* xo = xn + (size_t)row * DD;
#pragma unroll
  for (int i = 0; i < 3; i++) {
    int d = threadIdx.x + i * 256;
    xo[d] = (__bf16)((vals[i] - mu) * inv * g[d] + bta[d]);
  }
}

// ---------------- K2: bf16 MFMA GEMM  C = A(M,K) * B(N,K)^T + bias ----------
// MODE 0: plain out; MODE 3: fused qkv+bn epilogue (q/k elu+1 -> bf16 qkva,
//   v -> bf16 qkva, silu -> bf16 hbuf)
template <int BM, int MODE, bool HASBIAS, bool OUTBF>
__global__ __launch_bounds__(256) void gemm_mfma_kernel(
    const __bf16* __restrict__ A, const __bf16* __restrict__ Bw,
    const float* __restrict__ bias, void* __restrict__ Cv, void* __restrict__ C2,
    int M, int N, int K) {
  constexpr int MI = BM / 32;
  __shared__ __attribute__((aligned(16))) __bf16 As[BM * 64];
  __shared__ __attribute__((aligned(16))) __bf16 Bs[128 * 64];
  int m0 = blockIdx.y * BM, n0 = blockIdx.x * 128;
  int tid = threadIdx.x;
  int w = tid >> 6, lane = tid & 63;
  int wm = w >> 1, wn = w & 1;
  int quad = lane >> 4, l16 = lane & 15;
  int lrow = lane >> 3;
  int lchunk = (lane & 7) ^ lrow;
  int R0 = w * 8;

  floatx4 acc[MI][4];
#pragma unroll
  for (int i = 0; i < MI; i++)
#pragma unroll
    for (int j = 0; j < 4; j++) acc[i][j] = (floatx4)0.f;

  for (int k0 = 0; k0 < K; k0 += 64) {
    __syncthreads();
#pragma unroll
    for (int r = 0; r < BM / 32; r++) {
      int row = r * 32 + R0 + lrow;
      gl_lds16(A + (size_t)(m0 + row) * K + k0 + lchunk * 8, &As[(r * 32 + R0) * 64]);
    }
#pragma unroll
    for (int r = 0; r < 4; r++) {
      int row = r * 32 + R0 + lrow;
      gl_lds16(Bw + (size_t)(n0 + row) * K + k0 + lchunk * 8, &Bs[(r * 32 + R0) * 64]);
    }
    __syncthreads();
#pragma unroll
    for (int s = 0; s < 2; s++) {
      bf16x8 af[MI], bfr[4];
      int csw = (s << 2) + quad;
#pragma unroll
      for (int i = 0; i < MI; i++) {
        int m = wm * (BM / 2) + i * 16 + l16;
        af[i] = *(const bf16x8*)&As[m * 64 + (csw ^ (l16 & 7)) * 8];
      }
#pragma unroll
      for (int j = 0; j < 4; j++) {
        int n = wn * 64 + j * 16 + l16;
        bfr[j] = *(const bf16x8*)&Bs[n * 64 + (csw ^ (l16 & 7)) * 8];
      }
#pragma unroll
      for (int i = 0; i < MI; i++)
#pragma unroll
        for (int j = 0; j < 4; j++)
          acc[i][j] = __builtin_amdgcn_mfma_f32_16x16x32_bf16(af[i], bfr[j], acc[i][j], 0, 0, 0);
    }
  }
#pragma unroll
  for (int j = 0; j < 4; j++) {
    int gcol = n0 + wn * 64 + j * 16 + l16;
    if (MODE == 3) {
      if (gcol < 2304) {
        float bv = bias[gcol];
        bool isqk = gcol < 1536;
#pragma unroll
        for (int i = 0; i < MI; i++) {
          int grow = m0 + wm * (BM / 2) + i * 16 + quad * 4;
#pragma unroll
          for (int r = 0; r < 4; r++) {
            float v = acc[i][j][r] + bv;
            if (isqk) v = (v > 0.f) ? v + 1.f : expf(v);
            ((__bf16*)Cv)[(size_t)(grow + r) * 2304 + gcol] = (__bf16)v;
          }
        }
      } else {
        int hcol = gcol - 2304;
#pragma unroll
        for (int i = 0; i < MI; i++) {
          int grow = m0 + wm * (BM / 2) + i * 16 + quad * 4;
#pragma unroll
          for (int r = 0; r < 4; r++) {
            float v = acc[i][j][r];
            v = v / (1.f + expf(-v));
            ((__bf16*)C2)[(size_t)(grow + r) * 256 + hcol] = (__bf16)v;
          }
        }
      }
    } else {
      float bv = HASBIAS ? bias[gcol] : 0.f;
#pragma unroll
      for (int i = 0; i < MI; i++) {
        int grow = m0 + wm * (BM / 2) + i * 16 + quad * 4;
#pragma unroll
        for (int r = 0; r < 4; r++) {
          float v = acc[i][j][r] + bv;
          if (OUTBF) ((__bf16*)Cv)[(size_t)(grow + r) * N + gcol] = (__bf16)v;
          else       ((float*)Cv)[(size_t)(grow + r) * N + gcol] = v;
        }
      }
    }
  }
}

// ---------------- K3: params transform + df (fused, one block per bh) -------
__global__ __launch_bounds__(256) void params_df_kernel(
    const float* __restrict__ pp, const float* __restrict__ temp,
    float* __restrict__ gate, float* __restrict__ dec, float* __restrict__ dfb) {
  int bh = blockIdx.x;             // < 24
  int b = bh / HH, h = bh - b * HH;
  int tid = threadIdx.x;
  int lane = tid & 63, wid = tid >> 6;
  float tv = temp[0];
  const float PI = 3.14159265358979323846f;
  double ls[4];
  double lsum = 0.0;
#pragma unroll
  for (int i = 0; i < 4; i++) {
    int l = tid * 4 + i;
    int row = (b << 10) + l;
    const float* p = pp + (size_t)row * 128 + h * 5;
    float p0 = p[0], p1 = p[1], p2 = p[2], p3 = p[3], p4 = p[4];
    float sa = sigm(p0);
    float sp = tanhf(p1) * PI;
    float ca = sigm(p2);
    float cp = tanhf(p3) * PI;
    float dc = 0.3f + 0.65f * sigm(p4);
    float gt = sigm(sa * ca * cosf(sp - cp) * tv);
    gate[row * HH + h] = gt;
    dec[(bh << 10) + l] = dc;
    lsum += (double)logf(dc);
    ls[i] = lsum;
  }
  double run = lsum;
#pragma unroll
  for (int off = 1; off < 64; off <<= 1) {
    double n = __shfl_up(run, off, 64);
    if (lane >= off) run += n;
  }
  __shared__ double wsum[4];
  if (lane == 63) wsum[wid] = run;
  __syncthreads();
  double wexcl = 0.0;
  for (int k = 0; k < wid; k++) wexcl += wsum[k];
  double excl = wexcl + run - lsum;
  float* dfo = dfb + (bh << 10) + tid * 4;
#pragma unroll
  for (int i = 0; i < 4; i++) dfo[i] = expf((float)(excl + ls[i]));
}

// ---------------- K5: scan phase1 — heavy pass: recurrence + q-partials -----
// wave w owns KV rows [16w,16w+16); also emits out_local partials, z_local, P.
__global__ __launch_bounds__(256, 6) void scan_phase1(
    const __bf16* __restrict__ qkv, const float* __restrict__ dec,
    const float* __restrict__ df, const float* __restrict__ gate,
    __bf16* __restrict__ kvcs, float* __restrict__ zcs, float* __restrict__ Aarr,
    float* __restrict__ outp, float* __restrict__ zloc, float* __restrict__ pLoc) {
  int blk = blockIdx.x;            // bh*NC + c
  int bh = blk >> 6, c = blk & (NC - 1);
  int b = bh / HH, h = bh - b * HH;
  int tid = threadIdx.x;
  int w = tid >> 6, e = tid & 63;
  int t0 = c * CL;
  __shared__ __attribute__((aligned(16))) __bf16 qbuf[CL][64];
  __shared__ __attribute__((aligned(16))) __bf16 kbuf[CL][64];
  __shared__ __attribute__((aligned(16))) __bf16 vbuf[CL][64];
  __shared__ float sbuf[CL][4];
  // staging: w0: q0-7+k0-7, w1: q8-15+k8-15, w2: v0-7, w3: v8-15
  {
    int trow = ((w & 1) << 3) + (e >> 3);
    int chunk = e & 7;
    size_t rowbase = (size_t)(b * LL + t0 + trow) * 2304 + h * 64 + chunk * 8;
    if (w < 2) {
      gl_lds16(qkv + rowbase, &qbuf[(w & 1) << 3][0]);
      gl_lds16(qkv + rowbase + 768, &kbuf[(w & 1) << 3][0]);
    } else {
      gl_lds16(qkv + rowbase + 1536, &vbuf[(w & 1) << 3][0]);
    }
  }
  if (tid < CL) {
    int t = t0 + tid;
    float a = dec[bh * LL + t];
    float d = df[bh * LL + t];
    float r = d / (d + 1e-8f);
    float g = gate[(b * LL + t) * HH + h];
    sbuf[tid][0] = a; sbuf[tid][1] = r; sbuf[tid][2] = g * (1.f - a);
    sbuf[tid][3] = (1.f - a) * r;
  }
  __syncthreads();
  if (tid == 0) {                  // chunk-local decay prefix P_t and total A
    float run = 1.f;
#pragma unroll
    for (int t = 0; t < CL; t++) { run *= sbuf[t][0]; pLoc[blk * 16 + t] = run; }
    Aarr[blk] = run;
  }
  float KV[16];
#pragma unroll
  for (int d = 0; d < 16; d++) KV[d] = 0.f;
  float z = 0.f;
  for (int t = 0; t < CL; t++) {
    float a = sbuf[t][0], r = sbuf[t][1], cs = sbuf[t][2], w1r = sbuf[t][3];
    float vc = (float)vbuf[t][e] * cs;
    float onp = 0.f;
    bf16x8 k0 = *(const bf16x8*)&kbuf[t][w << 4];
    bf16x8 k1 = *(const bf16x8*)&kbuf[t][(w << 4) + 8];
    bf16x8 q0 = *(const bf16x8*)&qbuf[t][w << 4];
    bf16x8 q1 = *(const bf16x8*)&qbuf[t][(w << 4) + 8];
#pragma unroll
    for (int j = 0; j < 8; j++) {
      float u = clamp5((float)k0[j] * vc);
      float nv = fmaf(a, KV[j], r * u);
      KV[j] = nv;
      onp = fmaf((float)q0[j], nv, onp);
    }
#pragma unroll
    for (int j = 0; j < 8; j++) {
      float u = clamp5((float)k1[j] * vc);
      float nv = fmaf(a, KV[8 + j], r * u);
      KV[8 + j] = nv;
      onp = fmaf((float)q1[j], nv, onp);
    }
    z = fmaf(a, z, (float)kbuf[t][e] * w1r);
    outp[(size_t)blk * 4096 + t * 256 + (w << 6) + e] = onp;   // coalesced 1KB/t
    if ((t >> 2) == w) zloc[(size_t)blk * 1024 + t * 64 + e] = z;
  }
  __bf16* kvo = kvcs + (size_t)blk * 4096 + (w << 4) * 64 + e;
#pragma unroll
  for (int d = 0; d < 16; d++) kvo[d * 64] = (__bf16)KV[d];
  if (w == 0) zcs[blk * 64 + e] = z;
}

// ---------------- K6: sequential carry combine (in-place end->init) ---------
__global__ __launch_bounds__(256) void combine_kernel(
    const float* __restrict__ Aarr, __bf16* __restrict__ kv, float* __restrict__ z) {
  int g = blockIdx.x * 256 + threadIdx.x;
  if (g < NBH * 4096) {
    int bh = g >> 12, idx = g & 4095;
    const float* Ap = Aarr + bh * NC;
    __bf16* p = kv + (size_t)bh * NC * 4096 + idx;
    float carry = 0.f;
#pragma unroll 8
    for (int c = 0; c < NC; c++) {
      float endv = (float)p[(size_t)c * 4096];
      p[(size_t)c * 4096] = (__bf16)carry;
      carry = fmaf(Ap[c], carry, endv);
    }
  } else {
    int g2 = g - NBH * 4096;
    if (g2 >= NBH * 64) return;
    int bh = g2 >> 6, idx = g2 & 63;
    const float* Ap = Aarr + bh * NC;
    float* p = z + bh * NC * 64 + idx;
    float carry = 0.f;
#pragma unroll 8
    for (int c = 0; c < NC; c++) {
      float endv = p[c * 64];
      p[c * 64] = carry;
      carry = fmaf(Ap[c], carry, endv);
    }
  }
}

// ---------------- K7: scan phase3-lite — init matmul + den + head LN --------
// thread tid: t = tid>>4, e-cols (tid&15)*4 .. +3. No recurrence replay.
__global__ __launch_bounds__(256) void scan_phase3(
    const __bf16* __restrict__ qkv, const __bf16* __restrict__ kvcs,
    const float* __restrict__ zcs, const float* __restrict__ outp,
    const float* __restrict__ zloc, const float* __restrict__ pLoc,
    const float* __restrict__ mng, const float* __restrict__ mnb,
    __bf16* __restrict__ att) {
  int blk = blockIdx.x;
  int bh = blk >> 6, c = blk & (NC - 1);
  int b = bh / HH, h = bh - b * HH;
  int tid = threadIdx.x;
  int w = tid >> 6, e = tid & 63;
  int t0 = c * CL;
  __shared__ __attribute__((aligned(16))) __bf16 qbuf[CL][64];    // 2 KB
  __shared__ __attribute__((aligned(16))) __bf16 kvbuf[64][64];   // 8 KB
  // stage q (rows 0-15): waves 0,1
  if (w < 2) {
    int trow = ((w & 1) << 3) + (e >> 3);
    int chunk = e & 7;
    gl_lds16(qkv + (size_t)(b * LL + t0 + trow) * 2304 + h * 64 + chunk * 8,
             &qbuf[(w & 1) << 3][0]);
  }
  // stage KV_init: 8 wave-calls, m = w*2+j covers bf16 [m*512, m*512+512)
#pragma unroll
  for (int j = 0; j < 2; j++) {
    int m = (w << 1) | j;
    gl_lds16(kvcs + (size_t)blk * 4096 + m * 512 + e * 8, &kvbuf[m * 8][0]);
  }
  int t = tid >> 4;
  int e0 = (tid & 15) << 2;
  float P = pLoc[blk * 16 + t];
  float4 zi = *(const float4*)&zcs[blk * 64 + e0];
  float4 zl = *(const float4*)&zloc[(size_t)blk * 1024 + t * 64 + e0];
  float osum[4] = {0.f, 0.f, 0.f, 0.f};
#pragma unroll
  for (int ww = 0; ww < 4; ww++) {
    float4 o = *(const float4*)&outp[(size_t)blk * 4096 + t * 256 + ww * 64 + e0];
    osum[0] += o.x; osum[1] += o.y; osum[2] += o.z; osum[3] += o.w;
  }
  float4 mg = *(const float4*)&mng[e0];
  float4 mb = *(const float4*)&mnb[e0];
  __syncthreads();
  // init contribution: ic[x] = sum_d q[t][d] * kvbuf[d][e0+x]
  float ic[4] = {0.f, 0.f, 0.f, 0.f};
#pragma unroll
  for (int d0 = 0; d0 < 64; d0 += 8) {
    bf16x8 qv = *(const bf16x8*)&qbuf[t][d0];
#pragma unroll
    for (int j = 0; j < 8; j++) {
      bf16x4 kv = *(const bf16x4*)&kvbuf[d0 + j][e0];
      float qf = (float)qv[j];
#pragma unroll
      for (int x = 0; x < 4; x++) ic[x] = fmaf(qf, (float)kv[x], ic[x]);
    }
  }
  // assemble out_num, z(t), den pieces
  bf16x4 q4 = *(const bf16x4*)&qbuf[t][e0];
  float onum[4], zt[4];
  float s0 = 0.f, s1 = 0.f, s2 = 0.f;
  float zia[4] = {zi.x, zi.y, zi.z, zi.w};
  float zla[4] = {zl.x, zl.y, zl.z, zl.w};
#pragma unroll
  for (int x = 0; x < 4; x++) {
    onum[x] = fmaf(P, ic[x], osum[x]);
    float zv = fmaf(P, zia[x], zla[x]);
    zt[x] = __builtin_amdgcn_fmed3f(zv, -10000.f, 10000.f);
    s0 = fmaf((float)q4[x], zt[x], s0);
    s1 += onum[x];
    s2 = fmaf(onum[x], onum[x], s2);
  }
  // reduce over the 16 lanes sharing t (lanes differ in tid&15 only)
#pragma unroll
  for (int off = 1; off < 16; off <<= 1) {
    s0 += __shfl_xor(s0, off, 64);
    s1 += __shfl_xor(s1, off, 64);
    s2 += __shfl_xor(s2, off, 64);
  }
  float den = s0 + 1e-4f;
  float idn = 1.f / den;
  float mu = s1 * idn * (1.f / 64.f);
  float E2 = s2 * idn * idn * (1.f / 64.f);
  float var = E2 - mu * mu;
  float rst = rsqrtf(var + 1e-5f);
  float mga[4] = {mg.x, mg.y, mg.z, mg.w};
  float mba[4] = {mb.x, mb.y, mb.z, mb.w};
  bf16x4 ov;
#pragma unroll
  for (int x = 0; x < 4; x++) {
    float o = onum[x] * idn;
    ov[x] = (__bf16)((o - mu) * rst * mga[x] + mba[x]);
  }
  *(bf16x4*)&att[((size_t)(b * LL + t0 + t)) * DD + h * 64 + e0] = ov;
}

// ---------------------------------------------------------------------------
extern "C" void kernel_launch(void* const* d_in, const int* in_sizes, int n_in,
                              void* d_out, int out_size, void* d_ws, size_t ws_size,
                              hipStream_t stream) {
  (void)in_sizes; (void)n_in; (void)out_size; (void)ws_size;
  const float* x           = (const float*)d_in[0];
  const float* conv_w      = (const float*)d_in[1];
  const float* conv_b      = (const float*)d_in[2];
  const float* ln_g        = (const float*)d_in[3];
  const float* ln_b        = (const float*)d_in[4];
  const float* qkv_w       = (const float*)d_in[5];
  const float* qkv_b       = (const float*)d_in[6];
  const float* bn_w1       = (const float*)d_in[7];
  const float* bn_w2       = (const float*)d_in[8];
  const float* temperature = (const float*)d_in[9];
  const float* proj_w      = (const float*)d_in[10];
  const float* proj_b      = (const float*)d_in[11];
  const float* mn_g        = (const float*)d_in[12];
  const float* mn_b        = (const float*)d_in[13];

  float* y    = (float*)d_out;
  float* gate = y + 2 * 1024 * 768;      // outputs concatenated: y then gate

  char* ws = (char*)d_ws;
  __bf16* xn_bf   = (__bf16*)(ws);                 // 3.15 MB, reused as att_bf
  __bf16* att_bf  = xn_bf;                         // alias (xn dead before phase3)
  __bf16* qkva    = (__bf16*)(ws + 3145728);       // 9.44 MB bf16 (q|k|v, stride 2304)
  __bf16* hbuf_bf = (__bf16*)(ws + 12582912);      // 1.05 MB (2048x256 bf16)
  float*  pp      = (float*)(ws + 13631488);       // 1.05 MB (2048x128 fp32)
  float*  dec     = (float*)(ws + 14680064);       // 96 KB  (B,H,L)
  float*  dfb     = (float*)(ws + 14778368);       // 96 KB
  __bf16* kvcs    = (__bf16*)(ws + 14876672);      // 12.58 MB bf16 (end->init in place)
  __bf16* wqb_bf  = (__bf16*)(ws + 14876672);      // 3.93 MB alias (dead before phase1)
  float*  zcs     = (float*)(ws + 27459584);       // 384 KB
  float*  Aarr    = (float*)(ws + 27852800);       // 6 KB
  __bf16* projw_bf= (__bf16*)(ws + 27858944);      // 1.18 MB
  __bf16* w2p_bf  = (__bf16*)(ws + 29038592);      // 64 KB
  float*  outp    = (float*)(ws + 29104128);       // 25.17 MB
  float*  zloc    = (float*)(ws + 54269952);       // 6.29 MB
  float*  pLoc    = (float*)(ws + 60561408);       // 96 KB -> total ~60.7 MB

  // prep: conv+LN (blocks 0..2047) + weight converts (2048..4575)
  prep_kernel<<<4576, 256, 0, stream>>>(x, conv_w, conv_b, ln_g, ln_b, xn_bf,
                                        qkv_w, bn_w1, proj_w, bn_w2,
                                        wqb_bf, projw_bf, w2p_bf);

  // fused qkv+bn1 -> bf16 qkva + bf16 h
  gemm_mfma_kernel<64, 3, true, false><<<dim3(20, 32), 256, 0, stream>>>(
      xn_bf, wqb_bf, qkv_b, qkva, hbuf_bf, 2048, 2560, 768);

  // pp = h @ w2p.T  (N=128, rows>=60 zero-padded)
  gemm_mfma_kernel<64, 0, false, false><<<dim3(1, 32), 256, 0, stream>>>(
      hbuf_bf, w2p_bf, nullptr, pp, nullptr, 2048, 128, 256);

  params_df_kernel<<<NBH, 256, 0, stream>>>(pp, temperature, gate, dec, dfb);

  scan_phase1<<<NBH * NC, 256, 0, stream>>>(qkva, dec, dfb, gate, kvcs, zcs, Aarr,
                                            outp, zloc, pLoc);

  combine_kernel<<<390, 256, 0, stream>>>(Aarr, kvcs, zcs);

  scan_phase3<<<NBH * NC, 256, 0, stream>>>(qkva, kvcs, zcs, outp, zloc, pLoc,
                                            mn_g, mn_b, att_bf);

  // y = att @ proj_w.T + proj_b
  gemm_mfma_kernel<64, 0, true, false><<<dim3(6, 32), 256, 0, stream>>>(
      att_bf, projw_bf, proj_b, y, nullptr, 2048, 768, 768);
}

// Round 12
// 173.436 us; speedup vs baseline: 1.0376x; 1.0029x over previous
//
#include <hip/hip_runtime.h>
#include <hip/hip_cooperative_groups.h>
#include <math.h>

namespace cg = cooperative_groups;

#define LL 1024
#define DD 768
#define HH 12
#define CL 16
#define NC 64   // LL / CL
#define NBH 24  // B*H

typedef __bf16 bf16x8 __attribute__((ext_vector_type(8)));
typedef __bf16 bf16x4 __attribute__((ext_vector_type(4)));
typedef float floatx4 __attribute__((ext_vector_type(4)));

typedef const void __attribute__((address_space(1)))* gas_ptr;
typedef void __attribute__((address_space(3)))* las_ptr;

__device__ __forceinline__ void gl_lds16(const void* g, void* s) {
  __builtin_amdgcn_global_load_lds((gas_ptr)g, (las_ptr)s, 16, 0, 0);
}

__device__ __forceinline__ float wave_sum64(float v) {
#pragma unroll
  for (int off = 32; off; off >>= 1) v += __shfl_xor(v, off, 64);
  return v;
}

__device__ __forceinline__ float sigm(float x) { return 1.0f / (1.0f + expf(-x)); }
__device__ __forceinline__ float clamp5(float x) {
  return __builtin_amdgcn_fmed3f(x, -5.f, 5.f);
}

// ---------------- K1: prep — fused weight converts + conv+LN ----------------
__global__ __launch_bounds__(256) void prep_kernel(
    const float* __restrict__ x, const float* __restrict__ cw,
    const float* __restrict__ cb, const float* __restrict__ g,
    const float* __restrict__ bta, __bf16* __restrict__ xn,
    const float* __restrict__ qkvw, const float* __restrict__ bnw1,
    const float* __restrict__ projw, const float* __restrict__ w2,
    __bf16* __restrict__ wqb, __bf16* __restrict__ dp, __bf16* __restrict__ dw2) {
  if (blockIdx.x >= 2048) {             // ---- convert path ----
    int i = (blockIdx.x - 2048) * 256 + threadIdx.x;
    if (i >= 647168) return;
    bf16x4 o;
    if (i >= 638976) {                  // w2 pad region (128x256 bf16, fallback path)
      int off = i - 638976;
      if (off < 3840) {
        float4 v = ((const float4*)w2)[off];
        o[0] = (__bf16)v.x; o[1] = (__bf16)v.y; o[2] = (__bf16)v.z; o[3] = (__bf16)v.w;
      } else {
        o[0] = (__bf16)0.f; o[1] = (__bf16)0.f; o[2] = (__bf16)0.f; o[3] = (__bf16)0.f;
      }
      ((bf16x4*)dw2)[off] = o;
      return;
    }
    const float* s; __bf16* d; int off, soff;
    if (i < 442368)      { s = qkvw;  d = wqb; off = i; soff = i; }
    else if (i < 491520) { s = bnw1;  d = wqb; off = i; soff = i - 442368; }
    else                 { s = projw; d = dp;  off = i - 491520; soff = off; }
    float4 v = ((const float4*)s)[soff];
    o[0] = (__bf16)v.x; o[1] = (__bf16)v.y; o[2] = (__bf16)v.z; o[3] = (__bf16)v.w;
    ((bf16x4*)d)[off] = o;
    return;
  }
  // ---- conv + LN path ----
  int row = blockIdx.x;            // b*L + l
  int l = row & (LL - 1);
  const float* xr = x + (size_t)row * DD;
  __shared__ float red[16];
  float vals[3];
  float s = 0.f, ss = 0.f;
#pragma unroll
  for (int i = 0; i < 3; i++) {
    int d = threadIdx.x + i * 256;
    float x0 = xr[d];
    float xm1 = (l >= 1) ? xr[d - DD] : 0.f;
    float xm2 = (l >= 2) ? xr[d - 2 * DD] : 0.f;
    float c = xm2 * cw[d * 3 + 0] + xm1 * cw[d * 3 + 1] + x0 * cw[d * 3 + 2] + cb[d];
    float v = x0 + c;
    vals[i] = v; s += v; ss += v * v;
  }
  s = wave_sum64(s); ss = wave_sum64(ss);
  int wid = threadIdx.x >> 6;
  if ((threadIdx.x & 63) == 0) { red[wid * 2] = s; red[wid * 2 + 1] = ss; }
  __syncthreads();
  if (threadIdx.x == 0) {
    red[8] = red[0] + red[2] + red[4] + red[6];
    red[9] = red[1] + red[3] + red[5] + red[7];
  }
  __syncthreads();
  float mu = red[8] * (1.f / 768.f);
  float var = red[9] * (1.f / 768.f) - mu * mu;
  float inv = rsqrtf(var + 1e-5f);
  __bf16* xo = xn + (size_t)row * DD;
#pragma unroll
  for (int i = 0; i < 3; i++) {
    int d = threadIdx.x + i * 256;
    xo[d] = (__bf16)((vals[i] - mu) * inv * g[d] + bta[d]);
  }
}

// ---------------- K2: bf16 MFMA GEMM  C = A(M,K) * B(N,K)^T + bias ----------
template <int BM, int MODE, bool HASBIAS, bool OUTBF>
__global__ __launch_bounds__(256) void gemm_mfma_kernel(
    const __bf16* __restrict__ A, const __bf16* __restrict__ Bw,
    const float* __restrict__ bias, void* __restrict__ Cv, void* __restrict__ C2,
    int M, int N, int K) {
  constexpr int MI = BM / 32;
  __shared__ __attribute__((aligned(16))) __bf16 As[BM * 64];
  __shared__ __attribute__((aligned(16))) __bf16 Bs[128 * 64];
  int m0 = blockIdx.y * BM, n0 = blockIdx.x * 128;
  int tid = threadIdx.x;
  int w = tid >> 6, lane = tid & 63;
  int wm = w >> 1, wn = w & 1;
  int quad = lane >> 4, l16 = lane & 15;
  int lrow = lane >> 3;
  int lchunk = (lane & 7) ^ lrow;
  int R0 = w * 8;

  floatx4 acc[MI][4];
#pragma unroll
  for (int i = 0; i < MI; i++)
#pragma unroll
    for (int j = 0; j < 4; j++) acc[i][j] = (floatx4)0.f;

  for (int k0 = 0; k0 < K; k0 += 64) {
    __syncthreads();
#pragma unroll
    for (int r = 0; r < BM / 32; r++) {
      int row = r * 32 + R0 + lrow;
      gl_lds16(A + (size_t)(m0 + row) * K + k0 + lchunk * 8, &As[(r * 32 + R0) * 64]);
    }
#pragma unroll
    for (int r = 0; r < 4; r++) {
      int row = r * 32 + R0 + lrow;
      gl_lds16(Bw + (size_t)(n0 + row) * K + k0 + lchunk * 8, &Bs[(r * 32 + R0) * 64]);
    }
    __syncthreads();
#pragma unroll
    for (int s = 0; s < 2; s++) {
      bf16x8 af[MI], bfr[4];
      int csw = (s << 2) + quad;
#pragma unroll
      for (int i = 0; i < MI; i++) {
        int m = wm * (BM / 2) + i * 16 + l16;
        af[i] = *(const bf16x8*)&As[m * 64 + (csw ^ (l16 & 7)) * 8];
      }
#pragma unroll
      for (int j = 0; j < 4; j++) {
        int n = wn * 64 + j * 16 + l16;
        bfr[j] = *(const bf16x8*)&Bs[n * 64 + (csw ^ (l16 & 7)) * 8];
      }
#pragma unroll
      for (int i = 0; i < MI; i++)
#pragma unroll
        for (int j = 0; j < 4; j++)
          acc[i][j] = __builtin_amdgcn_mfma_f32_16x16x32_bf16(af[i], bfr[j], acc[i][j], 0, 0, 0);
    }
  }
#pragma unroll
  for (int j = 0; j < 4; j++) {
    int gcol = n0 + wn * 64 + j * 16 + l16;
    if (MODE == 3) {
      if (gcol < 2304) {
        float bv = bias[gcol];
        bool isqk = gcol < 1536;
#pragma unroll
        for (int i = 0; i < MI; i++) {
          int grow = m0 + wm * (BM / 2) + i * 16 + quad * 4;
#pragma unroll
          for (int r = 0; r < 4; r++) {
            float v = acc[i][j][r] + bv;
            if (isqk) v = (v > 0.f) ? v + 1.f : expf(v);
            ((__bf16*)Cv)[(size_t)(grow + r) * 2304 + gcol] = (__bf16)v;
          }
        }
      } else {
        int hcol = gcol - 2304;
#pragma unroll
        for (int i = 0; i < MI; i++) {
          int grow = m0 + wm * (BM / 2) + i * 16 + quad * 4;
#pragma unroll
          for (int r = 0; r < 4; r++) {
            float v = acc[i][j][r];
            v = v / (1.f + expf(-v));
            ((__bf16*)C2)[(size_t)(grow + r) * 256 + hcol] = (__bf16)v;
          }
        }
      }
    } else {
      float bv = HASBIAS ? bias[gcol] : 0.f;
#pragma unroll
      for (int i = 0; i < MI; i++) {
        int grow = m0 + wm * (BM / 2) + i * 16 + quad * 4;
#pragma unroll
        for (int r = 0; r < 4; r++) {
          float v = acc[i][j][r] + bv;
          if (OUTBF) ((__bf16*)Cv)[(size_t)(grow + r) * N + gcol] = (__bf16)v;
          else       ((float*)Cv)[(size_t)(grow + r) * N + gcol] = v;
        }
      }
    }
  }
}

// ============== COOPERATIVE fused scan: grid 768, 2 chunks/block ============
__global__ __launch_bounds__(256, 3) void scan_fused(
    const __bf16* __restrict__ qkv, const __bf16* __restrict__ hbuf,
    const float* __restrict__ w2, const float* __restrict__ temp,
    __bf16* __restrict__ kvcs, float* __restrict__ zcs,
    float* __restrict__ chLog, float* __restrict__ chA, float* __restrict__ chPre,
    float* __restrict__ outp, float* __restrict__ zloc, float* __restrict__ pLoc,
    const float* __restrict__ mng, const float* __restrict__ mnb,
    float* __restrict__ gate, __bf16* __restrict__ att) {
  cg::grid_group grid = cg::this_grid();
  int tid = threadIdx.x;
  int w = tid >> 6, e = tid & 63;

  __shared__ __attribute__((aligned(16))) __bf16 qbuf[CL][64];
  __shared__ __attribute__((aligned(16))) __bf16 kbuf[CL][64];
  __shared__ __attribute__((aligned(16))) __bf16 vbuf[CL][64];
  __shared__ __attribute__((aligned(16))) __bf16 hkv[64][64];  // h16 (P0) / kvbuf (P4)
  __shared__ float psb[CL][5];
  __shared__ float decL[2][CL], gtL[2][CL], lpreL[2][CL];
  __shared__ float sbuf[CL][4];

  // ======== P0: per-chunk params (h dots + transforms + local log-prefix) ====
#pragma unroll 1
  for (int ci = 0; ci < 2; ci++) {
    int gc = blockIdx.x + ci * 768;
    int bh = gc >> 6, c = gc & (NC - 1);
    int b = bh / HH, h = bh - b * HH;
    int t0 = c * CL;
    __syncthreads();                       // protect hkv/psb reuse
    {
      __bf16* h16 = &hkv[0][0];
      int cc0 = (w << 6) + e;
      gl_lds16(hbuf + (size_t)(b * LL + t0 + (cc0 >> 5)) * 256 + (cc0 & 31) * 8,
               (char*)h16 + (w << 10));
      int cc1 = 256 + cc0;
      gl_lds16(hbuf + (size_t)(b * LL + t0 + (cc1 >> 5)) * 256 + (cc1 & 31) * 8,
               (char*)h16 + 4096 + (w << 10));
    }
    __syncthreads();
    if (tid < 80) {
      int t = tid / 5, p = tid - t * 5;
      const float* wr = w2 + (h * 5 + p) * 256;
      const __bf16* hr = &hkv[0][0] + t * 256;
      float acc = 0.f;
#pragma unroll 8
      for (int k = 0; k < 256; k++) acc = fmaf((float)hr[k], wr[k], acc);
      psb[t][p] = acc;
    }
    __syncthreads();
    if (tid < CL) {
      int t = tid;
      const float PI = 3.14159265358979323846f;
      float sa = sigm(psb[t][0]), sp = tanhf(psb[t][1]) * PI;
      float ca = sigm(psb[t][2]), cp = tanhf(psb[t][3]) * PI;
      float dc = 0.3f + 0.65f * sigm(psb[t][4]);
      float gt = sigm(sa * ca * cosf(sp - cp) * temp[0]);
      gate[(size_t)(b * LL + t0 + t) * HH + h] = gt;
      decL[ci][t] = dc;
      gtL[ci][t] = gt;
      lpreL[ci][t] = logf(dc);
    }
    __syncthreads();
    if (tid == 0) {
      float run = 0.f;
#pragma unroll
      for (int t = 0; t < CL; t++) { run += lpreL[ci][t]; lpreL[ci][t] = run; }
      chLog[gc] = run;
    }
  }
  grid.sync();

  // ======== P1: per-bh prefix over 64 chunk log-sums ========
  if (blockIdx.x < NBH && tid < 64) {
    float v = chLog[blockIdx.x * 64 + tid];
    float run = v;
#pragma unroll
    for (int off = 1; off < 64; off <<= 1) {
      float n = __shfl_up(run, off, 64);
      if (tid >= off) run += n;
    }
    chPre[blockIdx.x * 64 + tid] = run - v;
    chA[blockIdx.x * 64 + tid] = expf(v);
  }
  grid.sync();

  // ======== P2: per-chunk phase1 recurrence + q-partials ========
#pragma unroll 1
  for (int ci = 0; ci < 2; ci++) {
    int gc = blockIdx.x + ci * 768;
    int bh = gc >> 6, c = gc & (NC - 1);
    int b = bh / HH, h = bh - b * HH;
    int t0 = c * CL;
    __syncthreads();                       // protect q/k/v + sbuf reuse
    {
      int trow = ((w & 1) << 3) + (e >> 3);
      int chunk = e & 7;
      size_t rowbase = (size_t)(b * LL + t0 + trow) * 2304 + h * 64 + chunk * 8;
      if (w < 2) {
        gl_lds16(qkv + rowbase, &qbuf[(w & 1) << 3][0]);
        gl_lds16(qkv + rowbase + 768, &kbuf[(w & 1) << 3][0]);
      } else {
        gl_lds16(qkv + rowbase + 1536, &vbuf[(w & 1) << 3][0]);
      }
    }
    if (tid < CL) {
      int t = tid;
      float base = chPre[gc];
      float df = expf(base + lpreL[ci][t]);
      float r = df / (df + 1e-8f);
      float a = decL[ci][t];
      float gt = gtL[ci][t];
      sbuf[t][0] = a; sbuf[t][1] = r; sbuf[t][2] = gt * (1.f - a);
      sbuf[t][3] = (1.f - a) * r;
      pLoc[gc * 16 + t] = expf(lpreL[ci][t]);   // chunk-local decay prefix P_t
    }
    __syncthreads();
    float KV[16];
#pragma unroll
    for (int d = 0; d < 16; d++) KV[d] = 0.f;
    float z = 0.f;
    for (int t = 0; t < CL; t++) {
      float a = sbuf[t][0], r = sbuf[t][1], cs = sbuf[t][2], w1r = sbuf[t][3];
      float vc = (float)vbuf[t][e] * cs;
      float onp = 0.f;
      bf16x8 k0 = *(const bf16x8*)&kbuf[t][w << 4];
      bf16x8 k1 = *(const bf16x8*)&kbuf[t][(w << 4) + 8];
      bf16x8 q0 = *(const bf16x8*)&qbuf[t][w << 4];
      bf16x8 q1 = *(const bf16x8*)&qbuf[t][(w << 4) + 8];
#pragma unroll
      for (int j = 0; j < 8; j++) {
        float u = clamp5((float)k0[j] * vc);
        float nv = fmaf(a, KV[j], r * u);
        KV[j] = nv;
        onp = fmaf((float)q0[j], nv, onp);
      }
#pragma unroll
      for (int j = 0; j < 8; j++) {
        float u = clamp5((float)k1[j] * vc);
        float nv = fmaf(a, KV[8 + j], r * u);
        KV[8 + j] = nv;
        onp = fmaf((float)q1[j], nv, onp);
      }
      z = fmaf(a, z, (float)kbuf[t][e] * w1r);
      outp[(size_t)gc * 4096 + t * 256 + (w << 6) + e] = onp;
      if ((t >> 2) == w) zloc[(size_t)gc * 1024 + t * 64 + e] = z;
    }
    __bf16* kvo = kvcs + (size_t)gc * 4096 + (w << 4) * 64 + e;
#pragma unroll
    for (int d = 0; d < 16; d++) kvo[d * 64] = (__bf16)KV[d];
    if (w == 0) zcs[gc * 64 + e] = z;
  }
  grid.sync();

  // ======== P3: carry combine (end -> init, in place) ========
  {
    int g = blockIdx.x * 256 + tid;
    if (g < NBH * 4096) {
      int cbh = g >> 12, idx = g & 4095;
      const float* Ap = chA + cbh * NC;
      __bf16* p = kvcs + (size_t)cbh * NC * 4096 + idx;
      float carry = 0.f;
#pragma unroll 8
      for (int cc = 0; cc < NC; cc++) {
        float endv = (float)p[(size_t)cc * 4096];
        p[(size_t)cc * 4096] = (__bf16)carry;
        carry = fmaf(Ap[cc], carry, endv);
      }
    } else if (g < NBH * 4096 + NBH * 64) {
      int g2 = g - NBH * 4096;
      int cbh = g2 >> 6, idx = g2 & 63;
      const float* Ap = chA + cbh * NC;
      float* p = zcs + cbh * NC * 64 + idx;
      float carry = 0.f;
#pragma unroll 8
      for (int cc = 0; cc < NC; cc++) {
        float endv = p[cc * 64];
        p[cc * 64] = carry;
        carry = fmaf(Ap[cc], carry, endv);
      }
    }
  }
  grid.sync();

  // ======== P4: per-chunk phase3-lite (init matmul + den + head LN) ========
#pragma unroll 1
  for (int ci = 0; ci < 2; ci++) {
    int gc = blockIdx.x + ci * 768;
    int bh = gc >> 6, c = gc & (NC - 1);
    int b = bh / HH, h = bh - b * HH;
    int t0 = c * CL;
    __syncthreads();                       // protect qbuf/hkv reuse
    if (w < 2) {
      int trow = ((w & 1) << 3) + (e >> 3);
      int chunk = e & 7;
      gl_lds16(qkv + (size_t)(b * LL + t0 + trow) * 2304 + h * 64 + chunk * 8,
               &qbuf[(w & 1) << 3][0]);
    }
#pragma unroll
    for (int j = 0; j < 2; j++) {
      int m = (w << 1) | j;
      gl_lds16(kvcs + (size_t)gc * 4096 + m * 512 + e * 8, &hkv[m * 8][0]);
    }
    int t = tid >> 4;
    int e0 = (tid & 15) << 2;
    float P = pLoc[gc * 16 + t];
    float4 zi = *(const float4*)&zcs[gc * 64 + e0];
    float4 zl = *(const float4*)&zloc[(size_t)gc * 1024 + t * 64 + e0];
    float osum[4] = {0.f, 0.f, 0.f, 0.f};
#pragma unroll
    for (int ww = 0; ww < 4; ww++) {
      float4 o = *(const float4*)&outp[(size_t)gc * 4096 + t * 256 + ww * 64 + e0];
      osum[0] += o.x; osum[1] += o.y; osum[2] += o.z; osum[3] += o.w;
    }
    float4 mg = *(const float4*)&mng[e0];
    float4 mb = *(const float4*)&mnb[e0];
    __syncthreads();
    float ic[4] = {0.f, 0.f, 0.f, 0.f};
#pragma unroll
    for (int d0 = 0; d0 < 64; d0 += 8) {
      bf16x8 qv = *(const bf16x8*)&qbuf[t][d0];
#pragma unroll
      for (int j = 0; j < 8; j++) {
        bf16x4 kv = *(const bf16x4*)&hkv[d0 + j][e0];
        float qf = (float)qv[j];
#pragma unroll
        for (int x = 0; x < 4; x++) ic[x] = fmaf(qf, (float)kv[x], ic[x]);
      }
    }
    bf16x4 q4 = *(const bf16x4*)&qbuf[t][e0];
    float onum[4], zt[4];
    float s0 = 0.f, s1 = 0.f, s2 = 0.f;
    float zia[4] = {zi.x, zi.y, zi.z, zi.w};
    float zla[4] = {zl.x, zl.y, zl.z, zl.w};
#pragma unroll
    for (int x = 0; x < 4; x++) {
      onum[x] = fmaf(P, ic[x], osum[x]);
      float zv = fmaf(P, zia[x], zla[x]);
      zt[x] = __builtin_amdgcn_fmed3f(zv, -10000.f, 10000.f);
      s0 = fmaf((float)q4[x], zt[x], s0);
      s1 += onum[x];
      s2 = fmaf(onum[x], onum[x], s2);
    }
#pragma unroll
    for (int off = 1; off < 16; off <<= 1) {
      s0 += __shfl_xor(s0, off, 64);
      s1 += __shfl_xor(s1, off, 64);
      s2 += __shfl_xor(s2, off, 64);
    }
    float den = s0 + 1e-4f;
    float idn = 1.f / den;
    float mu = s1 * idn * (1.f / 64.f);
    float E2 = s2 * idn * idn * (1.f / 64.f);
    float var = E2 - mu * mu;
    float rst = rsqrtf(var + 1e-5f);
    float mga[4] = {mg.x, mg.y, mg.z, mg.w};
    float mba[4] = {mb.x, mb.y, mb.z, mb.w};
    bf16x4 ov;
#pragma unroll
    for (int x = 0; x < 4; x++) {
      float o = onum[x] * idn;
      ov[x] = (__bf16)((o - mu) * rst * mga[x] + mba[x]);
    }
    *(bf16x4*)&att[((size_t)(b * LL + t0 + t)) * DD + h * 64 + e0] = ov;
  }
}

// ================== FALLBACK split-path kernels (R11, proven) ===============
__global__ __launch_bounds__(256) void params_df_kernel(
    const float* __restrict__ pp, const float* __restrict__ temp,
    float* __restrict__ gate, float* __restrict__ dec, float* __restrict__ dfb) {
  int bh = blockIdx.x;
  int b = bh / HH, h = bh - b * HH;
  int tid = threadIdx.x;
  int lane = tid & 63, wid = tid >> 6;
  float tv = temp[0];
  const float PI = 3.14159265358979323846f;
  double ls[4];
  double lsum = 0.0;
#pragma unroll
  for (int i = 0; i < 4; i++) {
    int l = tid * 4 + i;
    int row = (b << 10) + l;
    const float* p = pp + (size_t)row * 128 + h * 5;
    float sa = sigm(p[0]);
    float sp = tanhf(p[1]) * PI;
    float ca = sigm(p[2]);
    float cp = tanhf(p[3]) * PI;
    float dc = 0.3f + 0.65f * sigm(p[4]);
    float gt = sigm(sa * ca * cosf(sp - cp) * tv);
    gate[row * HH + h] = gt;
    dec[(bh << 10) + l] = dc;
    lsum += (double)logf(dc);
    ls[i] = lsum;
  }
  double run = lsum;
#pragma unroll
  for (int off = 1; off < 64; off <<= 1) {
    double n = __shfl_up(run, off, 64);
    if (lane >= off) run += n;
  }
  __shared__ double wsum[4];
  if (lane == 63) wsum[wid] = run;
  __syncthreads();
  double wexcl = 0.0;
  for (int k = 0; k < wid; k++) wexcl += wsum[k];
  double excl = wexcl + run - lsum;
  float* dfo = dfb + (bh << 10) + tid * 4;
#pragma unroll
  for (int i = 0; i < 4; i++) dfo[i] = expf((float)(excl + ls[i]));
}

__global__ __launch_bounds__(256, 6) void scan_phase1(
    const __bf16* __restrict__ qkv, const float* __restrict__ dec,
    const float* __restrict__ df, const float* __restrict__ gate,
    __bf16* __restrict__ kvcs, float* __restrict__ zcs, float* __restrict__ Aarr,
    float* __restrict__ outp, float* __restrict__ zloc, float* __restrict__ pLoc) {
  int blk = blockIdx.x;
  int bh = blk >> 6, c = blk & (NC - 1);
  int b = bh / HH, h = bh - b * HH;
  int tid = threadIdx.x;
  int w = tid >> 6, e = tid & 63;
  int t0 = c * CL;
  __shared__ __attribute__((aligned(16))) __bf16 qbuf[CL][64];
  __shared__ __attribute__((aligned(16))) __bf16 kbuf[CL][64];
  __shared__ __attribute__((aligned(16))) __bf16 vbuf[CL][64];
  __shared__ float sbuf[CL][4];
  {
    int trow = ((w & 1) << 3) + (e >> 3);
    int chunk = e & 7;
    size_t rowbase = (size_t)(b * LL + t0 + trow) * 2304 + h * 64 + chunk * 8;
    if (w < 2) {
      gl_lds16(qkv + rowbase, &qbuf[(w & 1) << 3][0]);
      gl_lds16(qkv + rowbase + 768, &kbuf[(w & 1) << 3][0]);
    } else {
      gl_lds16(qkv + rowbase + 1536, &vbuf[(w & 1) << 3][0]);
    }
  }
  if (tid < CL) {
    int t = t0 + tid;
    float a = dec[bh * LL + t];
    float d = df[bh * LL + t];
    float r = d / (d + 1e-8f);
    float g = gate[(b * LL + t) * HH + h];
    sbuf[tid][0] = a; sbuf[tid][1] = r; sbuf[tid][2] = g * (1.f - a);
    sbuf[tid][3] = (1.f - a) * r;
  }
  __syncthreads();
  if (tid == 0) {
    float run = 1.f;
#pragma unroll
    for (int t = 0; t < CL; t++) { run *= sbuf[t][0]; pLoc[blk * 16 + t] = run; }
    Aarr[blk] = run;
  }
  float KV[16];
#pragma unroll
  for (int d = 0; d < 16; d++) KV[d] = 0.f;
  float z = 0.f;
  for (int t = 0; t < CL; t++) {
    float a = sbuf[t][0], r = sbuf[t][1], cs = sbuf[t][2], w1r = sbuf[t][3];
    float vc = (float)vbuf[t][e] * cs;
    float onp = 0.f;
    bf16x8 k0 = *(const bf16x8*)&kbuf[t][w << 4];
    bf16x8 k1 = *(const bf16x8*)&kbuf[t][(w << 4) + 8];
    bf16x8 q0 = *(const bf16x8*)&qbuf[t][w << 4];
    bf16x8 q1 = *(const bf16x8*)&qbuf[t][(w << 4) + 8];
#pragma unroll
    for (int j = 0; j < 8; j++) {
      float u = clamp5((float)k0[j] * vc);
      float nv = fmaf(a, KV[j], r * u);
      KV[j] = nv;
      onp = fmaf((float)q0[j], nv, onp);
    }
#pragma unroll
    for (int j = 0; j < 8; j++) {
      float u = clamp5((float)k1[j] * vc);
      float nv = fmaf(a, KV[8 + j], r * u);
      KV[8 + j] = nv;
      onp = fmaf((float)q1[j], nv, onp);
    }
    z = fmaf(a, z, (float)kbuf[t][e] * w1r);
    outp[(size_t)blk * 4096 + t * 256 + (w << 6) + e] = onp;
    if ((t >> 2) == w) zloc[(size_t)blk * 1024 + t * 64 + e] = z;
  }
  __bf16* kvo = kvcs + (size_t)blk * 4096 + (w << 4) * 64 + e;
#pragma unroll
  for (int d = 0; d < 16; d++) kvo[d * 64] = (__bf16)KV[d];
  if (w == 0) zcs[blk * 64 + e] = z;
}

__global__ __launch_bounds__(256) void combine_kernel(
    const float* __restrict__ Aarr, __bf16* __restrict__ kv, float* __restrict__ z) {
  int g = blockIdx.x * 256 + threadIdx.x;
  if (g < NBH * 4096) {
    int bh = g >> 12, idx = g & 4095;
    const float* Ap = Aarr + bh * NC;
    __bf16* p = kv + (size_t)bh * NC * 4096 + idx;
    float carry = 0.f;
#pragma unroll 8
    for (int c = 0; c < NC; c++) {
      float endv = (float)p[(size_t)c * 4096];
      p[(size_t)c * 4096] = (__bf16)carry;
      carry = fmaf(Ap[c], carry, endv);
    }
  } else {
    int g2 = g - NBH * 4096;
    if (g2 >= NBH * 64) return;
    int bh = g2 >> 6, idx = g2 & 63;
    const float* Ap = Aarr + bh * NC;
    float* p = z + bh * NC * 64 + idx;
    float carry = 0.f;
#pragma unroll 8
    for (int c = 0; c < NC; c++) {
      float endv = p[c * 64];
      p[c * 64] = carry;
      carry = fmaf(Ap[c], carry, endv);
    }
  }
}

__global__ __launch_bounds__(256) void scan_phase3(
    const __bf16* __restrict__ qkv, const __bf16* __restrict__ kvcs,
    const float* __restrict__ zcs, const float* __restrict__ outp,
    const float* __restrict__ zloc, const float* __restrict__ pLoc,
    const float* __restrict__ mng, const float* __restrict__ mnb,
    __bf16* __restrict__ att) {
  int blk = blockIdx.x;
  int bh = blk >> 6, c = blk & (NC - 1);
  int b = bh / HH, h = bh - b * HH;
  int tid = threadIdx.x;
  int w = tid >> 6, e = tid & 63;
  int t0 = c * CL;
  __shared__ __attribute__((aligned(16))) __bf16 qbuf[CL][64];
  __shared__ __attribute__((aligned(16))) __bf16 kvbuf[64][64];
  if (w < 2) {
    int trow = ((w & 1) << 3) + (e >> 3);
    int chunk = e & 7;
    gl_lds16(qkv + (size_t)(b * LL + t0 + trow) * 2304 + h * 64 + chunk * 8,
             &qbuf[(w & 1) << 3][0]);
  }
#pragma unroll
  for (int j = 0; j < 2; j++) {
    int m = (w << 1) | j;
    gl_lds16(kvcs + (size_t)blk * 4096 + m * 512 + e * 8, &kvbuf[m * 8][0]);
  }
  int t = tid >> 4;
  int e0 = (tid & 15) << 2;
  float P = pLoc[blk * 16 + t];
  float4 zi = *(const float4*)&zcs[blk * 64 + e0];
  float4 zl = *(const float4*)&zloc[(size_t)blk * 1024 + t * 64 + e0];
  float osum[4] = {0.f, 0.f, 0.f, 0.f};
#pragma unroll
  for (int ww = 0; ww < 4; ww++) {
    float4 o = *(const float4*)&outp[(size_t)blk * 4096 + t * 256 + ww * 64 + e0];
    osum[0] += o.x; osum[1] += o.y; osum[2] += o.z; osum[3] += o.w;
  }
  float4 mg = *(const float4*)&mng[e0];
  float4 mb = *(const float4*)&mnb[e0];
  __syncthreads();
  float ic[4] = {0.f, 0.f, 0.f, 0.f};
#pragma unroll
  for (int d0 = 0; d0 < 64; d0 += 8) {
    bf16x8 qv = *(const bf16x8*)&qbuf[t][d0];
#pragma unroll
    for (int j = 0; j < 8; j++) {
      bf16x4 kv = *(const bf16x4*)&kvbuf[d0 + j][e0];
      float qf = (float)qv[j];
#pragma unroll
      for (int x = 0; x < 4; x++) ic[x] = fmaf(qf, (float)kv[x], ic[x]);
    }
  }
  bf16x4 q4 = *(const bf16x4*)&qbuf[t][e0];
  float onum[4], zt[4];
  float s0 = 0.f, s1 = 0.f, s2 = 0.f;
  float zia[4] = {zi.x, zi.y, zi.z, zi.w};
  float zla[4] = {zl.x, zl.y, zl.z, zl.w};
#pragma unroll
  for (int x = 0; x < 4; x++) {
    onum[x] = fmaf(P, ic[x], osum[x]);
    float zv = fmaf(P, zia[x], zla[x]);
    zt[x] = __builtin_amdgcn_fmed3f(zv, -10000.f, 10000.f);
    s0 = fmaf((float)q4[x], zt[x], s0);
    s1 += onum[x];
    s2 = fmaf(onum[x], onum[x], s2);
  }
#pragma unroll
  for (int off = 1; off < 16; off <<= 1) {
    s0 += __shfl_xor(s0, off, 64);
    s1 += __shfl_xor(s1, off, 64);
    s2 += __shfl_xor(s2, off, 64);
  }
  float den = s0 + 1e-4f;
  float idn = 1.f / den;
  float mu = s1 * idn * (1.f / 64.f);
  float E2 = s2 * idn * idn * (1.f / 64.f);
  float var = E2 - mu * mu;
  float rst = rsqrtf(var + 1e-5f);
  float mga[4] = {mg.x, mg.y, mg.z, mg.w};
  float mba[4] = {mb.x, mb.y, mb.z, mb.w};
  bf16x4 ov;
#pragma unroll
  for (int x = 0; x < 4; x++) {
    float o = onum[x] * idn;
    ov[x] = (__bf16)((o - mu) * rst * mga[x] + mba[x]);
  }
  *(bf16x4*)&att[((size_t)(b * LL + t0 + t)) * DD + h * 64 + e0] = ov;
}

// ---------------------------------------------------------------------------
extern "C" void kernel_launch(void* const* d_in, const int* in_sizes, int n_in,
                              void* d_out, int out_size, void* d_ws, size_t ws_size,
                              hipStream_t stream) {
  (void)in_sizes; (void)n_in; (void)out_size; (void)ws_size;
  const float* x           = (const float*)d_in[0];
  const float* conv_w      = (const float*)d_in[1];
  const float* conv_b      = (const float*)d_in[2];
  const float* ln_g        = (const float*)d_in[3];
  const float* ln_b        = (const float*)d_in[4];
  const float* qkv_w       = (const float*)d_in[5];
  const float* qkv_b       = (const float*)d_in[6];
  const float* bn_w1       = (const float*)d_in[7];
  const float* bn_w2       = (const float*)d_in[8];
  const float* temperature = (const float*)d_in[9];
  const float* proj_w      = (const float*)d_in[10];
  const float* proj_b      = (const float*)d_in[11];
  const float* mn_g        = (const float*)d_in[12];
  const float* mn_b        = (const float*)d_in[13];

  float* y    = (float*)d_out;
  float* gate = y + 2 * 1024 * 768;      // outputs concatenated: y then gate

  char* ws = (char*)d_ws;
  __bf16* xn_bf   = (__bf16*)(ws);                 // 3.15 MB, reused as att_bf
  __bf16* att_bf  = xn_bf;
  __bf16* qkva    = (__bf16*)(ws + 3145728);       // 9.44 MB
  __bf16* hbuf_bf = (__bf16*)(ws + 12582912);      // 1.05 MB
  float*  pp      = (float*)(ws + 13631488);       // 1.05 MB (fallback)
  float*  dec     = (float*)(ws + 14680064);       // 96 KB  (fallback)
  float*  dfb     = (float*)(ws + 14778368);       // 96 KB  (fallback)
  __bf16* kvcs    = (__bf16*)(ws + 14876672);      // 12.58 MB
  __bf16* wqb_bf  = (__bf16*)(ws + 14876672);      // 3.93 MB alias (dead before scan)
  float*  zcs     = (float*)(ws + 27459584);       // 384 KB
  float*  Aarr    = (float*)(ws + 27852800);       // 6 KB
  __bf16* projw_bf= (__bf16*)(ws + 27858944);      // 1.18 MB
  __bf16* w2p_bf  = (__bf16*)(ws + 29038592);      // 64 KB (fallback)
  float*  outp    = (float*)(ws + 29104128);       // 25.17 MB
  float*  zloc    = (float*)(ws + 54269952);       // 6.29 MB
  float*  pLoc    = (float*)(ws + 60561408);       // 96 KB
  float*  chLog   = (float*)(ws + 60659712);       // 6 KB
  float*  chA     = (float*)(ws + 60665856);       // 6 KB
  float*  chPre   = (float*)(ws + 60672000);       // 6 KB -> total ~60.7 MB

  prep_kernel<<<4576, 256, 0, stream>>>(x, conv_w, conv_b, ln_g, ln_b, xn_bf,
                                        qkv_w, bn_w1, proj_w, bn_w2,
                                        wqb_bf, projw_bf, w2p_bf);

  gemm_mfma_kernel<64, 3, true, false><<<dim3(20, 32), 256, 0, stream>>>(
      xn_bf, wqb_bf, qkv_b, qkva, hbuf_bf, 2048, 2560, 768);

  int coopBlocks = 0;
  (void)hipOccupancyMaxActiveBlocksPerMultiprocessor(
      &coopBlocks, reinterpret_cast<const void*>(scan_fused), 256, 0);

  if (coopBlocks >= 3) {
    void* kargs[] = {
      (void*)&qkva, (void*)&hbuf_bf, (void*)&bn_w2, (void*)&temperature,
      (void*)&kvcs, (void*)&zcs, (void*)&chLog, (void*)&chA, (void*)&chPre,
      (void*)&outp, (void*)&zloc, (void*)&pLoc,
      (void*)&mn_g, (void*)&mn_b, (void*)&gate, (void*)&att_bf
    };
    hipLaunchCooperativeKernel(reinterpret_cast<void*>(scan_fused),
                               dim3(768), dim3(256), kargs, 0, stream);
  } else {
    gemm_mfma_kernel<64, 0, false, false><<<dim3(1, 32), 256, 0, stream>>>(
        hbuf_bf, w2p_bf, nullptr, pp, nullptr, 2048, 128, 256);
    params_df_kernel<<<NBH, 256, 0, stream>>>(pp, temperature, gate, dec, dfb);
    scan_phase1<<<NBH * NC, 256, 0, stream>>>(qkva, dec, dfb, gate, kvcs, zcs,
                                              Aarr, outp, zloc, pLoc);
    combine_kernel<<<390, 256, 0, stream>>>(Aarr, kvcs, zcs);
    scan_phase3<<<NBH * NC, 256, 0, stream>>>(qkva, kvcs, zcs, outp, zloc, pLoc,
                                              mn_g, mn_b, att_bf);
  }

  gemm_mfma_kernel<64, 0, true, false><<<dim3(6, 32), 256, 0, stream>>>(
      att_bf, projw_bf, proj_b, y, nullptr, 2048, 768, 768);
}

// Round 13
// 170.514 us; speedup vs baseline: 1.0553x; 1.0171x over previous
//
#include <hip/hip_runtime.h>
#include <math.h>

#define LL 1024
#define DD 768
#define HH 12
#define CL 16
#define NC 64   // LL / CL
#define NBH 24  // B*H

typedef __bf16 bf16x8 __attribute__((ext_vector_type(8)));
typedef __bf16 bf16x4 __attribute__((ext_vector_type(4)));
typedef float floatx4 __attribute__((ext_vector_type(4)));

typedef const void __attribute__((address_space(1)))* gas_ptr;
typedef void __attribute__((address_space(3)))* las_ptr;

__device__ __forceinline__ void gl_lds16(const void* g, void* s) {
  __builtin_amdgcn_global_load_lds((gas_ptr)g, (las_ptr)s, 16, 0, 0);
}

__device__ __forceinline__ float wave_sum64(float v) {
#pragma unroll
  for (int off = 32; off; off >>= 1) v += __shfl_xor(v, off, 64);
  return v;
}

__device__ __forceinline__ float sigm(float x) { return 1.0f / (1.0f + expf(-x)); }
__device__ __forceinline__ float clamp5(float x) {
  return __builtin_amdgcn_fmed3f(x, -5.f, 5.f);
}

// ---------------- K1: prep — fused weight converts + conv+LN ----------------
__global__ __launch_bounds__(256) void prep_kernel(
    const float* __restrict__ x, const float* __restrict__ cw,
    const float* __restrict__ cb, const float* __restrict__ g,
    const float* __restrict__ bta, __bf16* __restrict__ xn,
    const float* __restrict__ qkvw, const float* __restrict__ bnw1,
    const float* __restrict__ projw, const float* __restrict__ w2,
    __bf16* __restrict__ wqb, __bf16* __restrict__ dp, __bf16* __restrict__ dw2) {
  if (blockIdx.x >= 2048) {             // ---- convert path ----
    int i = (blockIdx.x - 2048) * 256 + threadIdx.x;
    if (i >= 647168) return;
    bf16x4 o;
    if (i >= 638976) {                  // w2 pad region (128x256 bf16)
      int off = i - 638976;
      if (off < 3840) {
        float4 v = ((const float4*)w2)[off];
        o[0] = (__bf16)v.x; o[1] = (__bf16)v.y; o[2] = (__bf16)v.z; o[3] = (__bf16)v.w;
      } else {
        o[0] = (__bf16)0.f; o[1] = (__bf16)0.f; o[2] = (__bf16)0.f; o[3] = (__bf16)0.f;
      }
      ((bf16x4*)dw2)[off] = o;
      return;
    }
    const float* s; __bf16* d; int off, soff;
    if (i < 442368)      { s = qkvw;  d = wqb; off = i; soff = i; }
    else if (i < 491520) { s = bnw1;  d = wqb; off = i; soff = i - 442368; }
    else                 { s = projw; d = dp;  off = i - 491520; soff = off; }
    float4 v = ((const float4*)s)[soff];
    o[0] = (__bf16)v.x; o[1] = (__bf16)v.y; o[2] = (__bf16)v.z; o[3] = (__bf16)v.w;
    ((bf16x4*)d)[off] = o;
    return;
  }
  // ---- conv + LN path ----
  int row = blockIdx.x;            // b*L + l
  int l = row & (LL - 1);
  const float* xr = x + (size_t)row * DD;
  __shared__ float red[16];
  float vals[3];
  float s = 0.f, ss = 0.f;
#pragma unroll
  for (int i = 0; i < 3; i++) {
    int d = threadIdx.x + i * 256;
    float x0 = xr[d];
    float xm1 = (l >= 1) ? xr[d - DD] : 0.f;
    float xm2 = (l >= 2) ? xr[d - 2 * DD] : 0.f;
    float c = xm2 * cw[d * 3 + 0] + xm1 * cw[d * 3 + 1] + x0 * cw[d * 3 + 2] + cb[d];
    float v = x0 + c;
    vals[i] = v; s += v; ss += v * v;
  }
  s = wave_sum64(s); ss = wave_sum64(ss);
  int wid = threadIdx.x >> 6;
  if ((threadIdx.x & 63) == 0) { red[wid * 2] = s; red[wid * 2 + 1] = ss; }
  __syncthreads();
  if (threadIdx.x == 0) {
    red[8] = red[0] + red[2] + red[4] + red[6];
    red[9] = red[1] + red[3] + red[5] + red[7];
  }
  __syncthreads();
  float mu = red[8] * (1.f / 768.f);
  float var = red[9] * (1.f / 768.f) - mu * mu;
  float inv = rsqrtf(var + 1e-5f);
  __bf16* xo = xn + (size_t)row * DD;
#pragma unroll
  for (int i = 0; i < 3; i++) {
    int d = threadIdx.x + i * 256;
    xo[d] = (__bf16)((vals[i] - mu) * inv * g[d] + bta[d]);
  }
}

// ---------------- K2: bf16 MFMA GEMM  C = A(M,K) * B(N,K)^T + bias ----------
template <int BM, int MODE, bool HASBIAS, bool OUTBF>
__global__ __launch_bounds__(256) void gemm_mfma_kernel(
    const __bf16* __restrict__ A, const __bf16* __restrict__ Bw,
    const float* __restrict__ bias, void* __restrict__ Cv, void* __restrict__ C2,
    int M, int N, int K) {
  constexpr int MI = BM / 32;
  __shared__ __attribute__((aligned(16))) __bf16 As[BM * 64];
  __shared__ __attribute__((aligned(16))) __bf16 Bs[128 * 64];
  int m0 = blockIdx.y * BM, n0 = blockIdx.x * 128;
  int tid = threadIdx.x;
  int w = tid >> 6, lane = tid & 63;
  int wm = w >> 1, wn = w & 1;
  int quad = lane >> 4, l16 = lane & 15;
  int lrow = lane >> 3;
  int lchunk = (lane & 7) ^ lrow;
  int R0 = w * 8;

  floatx4 acc[MI][4];
#pragma unroll
  for (int i = 0; i < MI; i++)
#pragma unroll
    for (int j = 0; j < 4; j++) acc[i][j] = (floatx4)0.f;

  for (int k0 = 0; k0 < K; k0 += 64) {
    __syncthreads();
#pragma unroll
    for (int r = 0; r < BM / 32; r++) {
      int row = r * 32 + R0 + lrow;
      gl_lds16(A + (size_t)(m0 + row) * K + k0 + lchunk * 8, &As[(r * 32 + R0) * 64]);
    }
#pragma unroll
    for (int r = 0; r < 4; r++) {
      int row = r * 32 + R0 + lrow;
      gl_lds16(Bw + (size_t)(n0 + row) * K + k0 + lchunk * 8, &Bs[(r * 32 + R0) * 64]);
    }
    __syncthreads();
#pragma unroll
    for (int s = 0; s < 2; s++) {
      bf16x8 af[MI], bfr[4];
      int csw = (s << 2) + quad;
#pragma unroll
      for (int i = 0; i < MI; i++) {
        int m = wm * (BM / 2) + i * 16 + l16;
        af[i] = *(const bf16x8*)&As[m * 64 + (csw ^ (l16 & 7)) * 8];
      }
#pragma unroll
      for (int j = 0; j < 4; j++) {
        int n = wn * 64 + j * 16 + l16;
        bfr[j] = *(const bf16x8*)&Bs[n * 64 + (csw ^ (l16 & 7)) * 8];
      }
#pragma unroll
      for (int i = 0; i < MI; i++)
#pragma unroll
        for (int j = 0; j < 4; j++)
          acc[i][j] = __builtin_amdgcn_mfma_f32_16x16x32_bf16(af[i], bfr[j], acc[i][j], 0, 0, 0);
    }
  }
#pragma unroll
  for (int j = 0; j < 4; j++) {
    int gcol = n0 + wn * 64 + j * 16 + l16;
    if (MODE == 3) {
      if (gcol < 2304) {
        float bv = bias[gcol];
        bool isqk = gcol < 1536;
#pragma unroll
        for (int i = 0; i < MI; i++) {
          int grow = m0 + wm * (BM / 2) + i * 16 + quad * 4;
#pragma unroll
          for (int r = 0; r < 4; r++) {
            float v = acc[i][j][r] + bv;
            if (isqk) v = (v > 0.f) ? v + 1.f : expf(v);
            ((__bf16*)Cv)[(size_t)(grow + r) * 2304 + gcol] = (__bf16)v;
          }
        }
      } else {
        int hcol = gcol - 2304;
#pragma unroll
        for (int i = 0; i < MI; i++) {
          int grow = m0 + wm * (BM / 2) + i * 16 + quad * 4;
#pragma unroll
          for (int r = 0; r < 4; r++) {
            float v = acc[i][j][r];
            v = v / (1.f + expf(-v));
            ((__bf16*)C2)[(size_t)(grow + r) * 256 + hcol] = (__bf16)v;
          }
        }
      }
    } else {
      float bv = HASBIAS ? bias[gcol] : 0.f;
#pragma unroll
      for (int i = 0; i < MI; i++) {
        int grow = m0 + wm * (BM / 2) + i * 16 + quad * 4;
#pragma unroll
        for (int r = 0; r < 4; r++) {
          float v = acc[i][j][r] + bv;
          if (OUTBF) ((__bf16*)Cv)[(size_t)(grow + r) * N + gcol] = (__bf16)v;
          else       ((float*)Cv)[(size_t)(grow + r) * N + gcol] = v;
        }
      }
    }
  }
}

// ---------------- K3: params transform + df (fused, one block per bh) -------
__global__ __launch_bounds__(256) void params_df_kernel(
    const float* __restrict__ pp, const float* __restrict__ temp,
    float* __restrict__ gate, float* __restrict__ dec, float* __restrict__ dfb) {
  int bh = blockIdx.x;
  int b = bh / HH, h = bh - b * HH;
  int tid = threadIdx.x;
  int lane = tid & 63, wid = tid >> 6;
  float tv = temp[0];
  const float PI = 3.14159265358979323846f;
  double ls[4];
  double lsum = 0.0;
#pragma unroll
  for (int i = 0; i < 4; i++) {
    int l = tid * 4 + i;
    int row = (b << 10) + l;
    const float* p = pp + (size_t)row * 128 + h * 5;
    float sa = sigm(p[0]);
    float sp = tanhf(p[1]) * PI;
    float ca = sigm(p[2]);
    float cp = tanhf(p[3]) * PI;
    float dc = 0.3f + 0.65f * sigm(p[4]);
    float gt = sigm(sa * ca * cosf(sp - cp) * tv);
    gate[row * HH + h] = gt;
    dec[(bh << 10) + l] = dc;
    lsum += (double)logf(dc);
    ls[i] = lsum;
  }
  double run = lsum;
#pragma unroll
  for (int off = 1; off < 64; off <<= 1) {
    double n = __shfl_up(run, off, 64);
    if (lane >= off) run += n;
  }
  __shared__ double wsum[4];
  if (lane == 63) wsum[wid] = run;
  __syncthreads();
  double wexcl = 0.0;
  for (int k = 0; k < wid; k++) wexcl += wsum[k];
  double excl = wexcl + run - lsum;
  float* dfo = dfb + (bh << 10) + tid * 4;
#pragma unroll
  for (int i = 0; i < 4; i++) dfo[i] = expf((float)(excl + ls[i]));
}

// ---------------- K5: scan phase1 — recurrence + wave-summed q-partials -----
// wave w owns KV rows [16w,16w+16); out_local summed over waves in LDS before
// store (outp 6.3 MB instead of 25 MB).
__global__ __launch_bounds__(256, 6) void scan_phase1(
    const __bf16* __restrict__ qkv, const float* __restrict__ dec,
    const float* __restrict__ df, const float* __restrict__ gate,
    __bf16* __restrict__ kvcs, float* __restrict__ zcs, float* __restrict__ Aarr,
    float* __restrict__ outp, float* __restrict__ zloc, float* __restrict__ pLoc) {
  int blk = blockIdx.x;
  int bh = blk >> 6, c = blk & (NC - 1);
  int b = bh / HH, h = bh - b * HH;
  int tid = threadIdx.x;
  int w = tid >> 6, e = tid & 63;
  int t0 = c * CL;
  __shared__ __attribute__((aligned(16))) __bf16 qbuf[CL][64];
  __shared__ __attribute__((aligned(16))) __bf16 kbuf[CL][64];
  __shared__ __attribute__((aligned(16))) __bf16 vbuf[CL][64];
  __shared__ float sbuf[CL][4];
  __shared__ float pbuf[8][4][64];   // half-buffered wave partials (8 KB)
  {
    int trow = ((w & 1) << 3) + (e >> 3);
    int chunk = e & 7;
    size_t rowbase = (size_t)(b * LL + t0 + trow) * 2304 + h * 64 + chunk * 8;
    if (w < 2) {
      gl_lds16(qkv + rowbase, &qbuf[(w & 1) << 3][0]);
      gl_lds16(qkv + rowbase + 768, &kbuf[(w & 1) << 3][0]);
    } else {
      gl_lds16(qkv + rowbase + 1536, &vbuf[(w & 1) << 3][0]);
    }
  }
  if (tid < CL) {
    int t = t0 + tid;
    float a = dec[bh * LL + t];
    float d = df[bh * LL + t];
    float r = d / (d + 1e-8f);
    float g = gate[(b * LL + t) * HH + h];
    sbuf[tid][0] = a; sbuf[tid][1] = r; sbuf[tid][2] = g * (1.f - a);
    sbuf[tid][3] = (1.f - a) * r;
  }
  __syncthreads();
  if (tid == 0) {
    float run = 1.f;
#pragma unroll
    for (int t = 0; t < CL; t++) { run *= sbuf[t][0]; pLoc[blk * 16 + t] = run; }
    Aarr[blk] = run;
  }
  float KV[16];
#pragma unroll
  for (int d = 0; d < 16; d++) KV[d] = 0.f;
  float z = 0.f;
#pragma unroll
  for (int half = 0; half < 2; half++) {
    for (int tt = 0; tt < 8; tt++) {
      int t = (half << 3) + tt;
      float a = sbuf[t][0], r = sbuf[t][1], cs = sbuf[t][2], w1r = sbuf[t][3];
      float vc = (float)vbuf[t][e] * cs;
      float onp = 0.f;
      bf16x8 k0 = *(const bf16x8*)&kbuf[t][w << 4];
      bf16x8 k1 = *(const bf16x8*)&kbuf[t][(w << 4) + 8];
      bf16x8 q0 = *(const bf16x8*)&qbuf[t][w << 4];
      bf16x8 q1 = *(const bf16x8*)&qbuf[t][(w << 4) + 8];
#pragma unroll
      for (int j = 0; j < 8; j++) {
        float u = clamp5((float)k0[j] * vc);
        float nv = fmaf(a, KV[j], r * u);
        KV[j] = nv;
        onp = fmaf((float)q0[j], nv, onp);
      }
#pragma unroll
      for (int j = 0; j < 8; j++) {
        float u = clamp5((float)k1[j] * vc);
        float nv = fmaf(a, KV[8 + j], r * u);
        KV[8 + j] = nv;
        onp = fmaf((float)q1[j], nv, onp);
      }
      pbuf[tt][w][e] = onp;
      z = fmaf(a, z, (float)kbuf[t][e] * w1r);
      if ((t >> 2) == w) zloc[(size_t)blk * 1024 + t * 64 + e] = z;
    }
    __syncthreads();
    // wave w sums+stores tt = 2w, 2w+1 of this half
#pragma unroll
    for (int i = 0; i < 2; i++) {
      int tt = (w << 1) + i;
      int t = (half << 3) + tt;
      float on = pbuf[tt][0][e] + pbuf[tt][1][e] + pbuf[tt][2][e] + pbuf[tt][3][e];
      outp[(size_t)blk * 1024 + t * 64 + e] = on;
    }
    if (half == 0) __syncthreads();
  }
  __bf16* kvo = kvcs + (size_t)blk * 4096 + (w << 4) * 64 + e;
#pragma unroll
  for (int d = 0; d < 16; d++) kvo[d * 64] = (__bf16)KV[d];
  if (w == 0) zcs[blk * 64 + e] = z;
}

// ---------------- K6: sequential carry combine (in-place end->init) ---------
__global__ __launch_bounds__(256) void combine_kernel(
    const float* __restrict__ Aarr, __bf16* __restrict__ kv, float* __restrict__ z) {
  int g = blockIdx.x * 256 + threadIdx.x;
  if (g < NBH * 4096) {
    int bh = g >> 12, idx = g & 4095;
    const float* Ap = Aarr + bh * NC;
    __bf16* p = kv + (size_t)bh * NC * 4096 + idx;
    float carry = 0.f;
#pragma unroll 8
    for (int c = 0; c < NC; c++) {
      float endv = (float)p[(size_t)c * 4096];
      p[(size_t)c * 4096] = (__bf16)carry;
      carry = fmaf(Ap[c], carry, endv);
    }
  } else {
    int g2 = g - NBH * 4096;
    if (g2 >= NBH * 64) return;
    int bh = g2 >> 6, idx = g2 & 63;
    const float* Ap = Aarr + bh * NC;
    float* p = z + bh * NC * 64 + idx;
    float carry = 0.f;
#pragma unroll 8
    for (int c = 0; c < NC; c++) {
      float endv = p[c * 64];
      p[c * 64] = carry;
      carry = fmaf(Ap[c], carry, endv);
    }
  }
}

// ---------------- K7: scan phase3-lite — init matmul + den + head LN --------
__global__ __launch_bounds__(256) void scan_phase3(
    const __bf16* __restrict__ qkv, const __bf16* __restrict__ kvcs,
    const float* __restrict__ zcs, const float* __restrict__ outp,
    const float* __restrict__ zloc, const float* __restrict__ pLoc,
    const float* __restrict__ mng, const float* __restrict__ mnb,
    __bf16* __restrict__ att) {
  int blk = blockIdx.x;
  int bh = blk >> 6, c = blk & (NC - 1);
  int b = bh / HH, h = bh - b * HH;
  int tid = threadIdx.x;
  int w = tid >> 6, e = tid & 63;
  int t0 = c * CL;
  __shared__ __attribute__((aligned(16))) __bf16 qbuf[CL][64];
  __shared__ __attribute__((aligned(16))) __bf16 kvbuf[64][64];
  if (w < 2) {
    int trow = ((w & 1) << 3) + (e >> 3);
    int chunk = e & 7;
    gl_lds16(qkv + (size_t)(b * LL + t0 + trow) * 2304 + h * 64 + chunk * 8,
             &qbuf[(w & 1) << 3][0]);
  }
#pragma unroll
  for (int j = 0; j < 2; j++) {
    int m = (w << 1) | j;
    gl_lds16(kvcs + (size_t)blk * 4096 + m * 512 + e * 8, &kvbuf[m * 8][0]);
  }
  int t = tid >> 4;
  int e0 = (tid & 15) << 2;
  float P = pLoc[blk * 16 + t];
  float4 zi = *(const float4*)&zcs[blk * 64 + e0];
  float4 zl = *(const float4*)&zloc[(size_t)blk * 1024 + t * 64 + e0];
  float4 os = *(const float4*)&outp[(size_t)blk * 1024 + t * 64 + e0];
  float osum[4] = {os.x, os.y, os.z, os.w};
  float4 mg = *(const float4*)&mng[e0];
  float4 mb = *(const float4*)&mnb[e0];
  __syncthreads();
  float ic[4] = {0.f, 0.f, 0.f, 0.f};
#pragma unroll
  for (int d0 = 0; d0 < 64; d0 += 8) {
    bf16x8 qv = *(const bf16x8*)&qbuf[t][d0];
#pragma unroll
    for (int j = 0; j < 8; j++) {
      bf16x4 kv = *(const bf16x4*)&kvbuf[d0 + j][e0];
      float qf = (float)qv[j];
#pragma unroll
      for (int x = 0; x < 4; x++) ic[x] = fmaf(qf, (float)kv[x], ic[x]);
    }
  }
  bf16x4 q4 = *(const bf16x4*)&qbuf[t][e0];
  float onum[4], zt[4];
  float s0 = 0.f, s1 = 0.f, s2 = 0.f;
  float zia[4] = {zi.x, zi.y, zi.z, zi.w};
  float zla[4] = {zl.x, zl.y, zl.z, zl.w};
#pragma unroll
  for (int x = 0; x < 4; x++) {
    onum[x] = fmaf(P, ic[x], osum[x]);
    float zv = fmaf(P, zia[x], zla[x]);
    zt[x] = __builtin_amdgcn_fmed3f(zv, -10000.f, 10000.f);
    s0 = fmaf((float)q4[x], zt[x], s0);
    s1 += onum[x];
    s2 = fmaf(onum[x], onum[x], s2);
  }
#pragma unroll
  for (int off = 1; off < 16; off <<= 1) {
    s0 += __shfl_xor(s0, off, 64);
    s1 += __shfl_xor(s1, off, 64);
    s2 += __shfl_xor(s2, off, 64);
  }
  float den = s0 + 1e-4f;
  float idn = 1.f / den;
  float mu = s1 * idn * (1.f / 64.f);
  float E2 = s2 * idn * idn * (1.f / 64.f);
  float var = E2 - mu * mu;
  float rst = rsqrtf(var + 1e-5f);
  float mga[4] = {mg.x, mg.y, mg.z, mg.w};
  float mba[4] = {mb.x, mb.y, mb.z, mb.w};
  bf16x4 ov;
#pragma unroll
  for (int x = 0; x < 4; x++) {
    float o = onum[x] * idn;
    ov[x] = (__bf16)((o - mu) * rst * mga[x] + mba[x]);
  }
  *(bf16x4*)&att[((size_t)(b * LL + t0 + t)) * DD + h * 64 + e0] = ov;
}

// ---------------------------------------------------------------------------
extern "C" void kernel_launch(void* const* d_in, const int* in_sizes, int n_in,
                              void* d_out, int out_size, void* d_ws, size_t ws_size,
                              hipStream_t stream) {
  (void)in_sizes; (void)n_in; (void)out_size; (void)ws_size;
  const float* x           = (const float*)d_in[0];
  const float* conv_w      = (const float*)d_in[1];
  const float* conv_b      = (const float*)d_in[2];
  const float* ln_g        = (const float*)d_in[3];
  const float* ln_b        = (const float*)d_in[4];
  const float* qkv_w       = (const float*)d_in[5];
  const float* qkv_b       = (const float*)d_in[6];
  const float* bn_w1       = (const float*)d_in[7];
  const float* bn_w2       = (const float*)d_in[8];
  const float* temperature = (const float*)d_in[9];
  const float* proj_w      = (const float*)d_in[10];
  const float* proj_b      = (const float*)d_in[11];
  const float* mn_g        = (const float*)d_in[12];
  const float* mn_b        = (const float*)d_in[13];

  float* y    = (float*)d_out;
  float* gate = y + 2 * 1024 * 768;      // outputs concatenated: y then gate

  char* ws = (char*)d_ws;
  __bf16* xn_bf   = (__bf16*)(ws);                 // 3.15 MB, reused as att_bf
  __bf16* att_bf  = xn_bf;
  __bf16* qkva    = (__bf16*)(ws + 3145728);       // 9.44 MB
  __bf16* hbuf_bf = (__bf16*)(ws + 12582912);      // 1.05 MB
  float*  pp      = (float*)(ws + 13631488);       // 1.05 MB
  float*  dec     = (float*)(ws + 14680064);       // 96 KB
  float*  dfb     = (float*)(ws + 14778368);       // 96 KB
  __bf16* kvcs    = (__bf16*)(ws + 14876672);      // 12.58 MB
  __bf16* wqb_bf  = (__bf16*)(ws + 14876672);      // 3.93 MB alias (dead before scan)
  float*  zcs     = (float*)(ws + 27459584);       // 384 KB
  float*  Aarr    = (float*)(ws + 27852800);       // 6 KB
  __bf16* projw_bf= (__bf16*)(ws + 27858944);      // 1.18 MB
  __bf16* w2p_bf  = (__bf16*)(ws + 29038592);      // 64 KB
  float*  outp    = (float*)(ws + 29104128);       // 6.29 MB (wave-summed)
  float*  zloc    = (float*)(ws + 35395584);       // 6.29 MB
  float*  pLoc    = (float*)(ws + 41687040);       // 96 KB -> total ~41.8 MB

  prep_kernel<<<4576, 256, 0, stream>>>(x, conv_w, conv_b, ln_g, ln_b, xn_bf,
                                        qkv_w, bn_w1, proj_w, bn_w2,
                                        wqb_bf, projw_bf, w2p_bf);

  gemm_mfma_kernel<64, 3, true, false><<<dim3(20, 32), 256, 0, stream>>>(
      xn_bf, wqb_bf, qkv_b, qkva, hbuf_bf, 2048, 2560, 768);

  gemm_mfma_kernel<64, 0, false, false><<<dim3(1, 32), 256, 0, stream>>>(
      hbuf_bf, w2p_bf, nullptr, pp, nullptr, 2048, 128, 256);

  params_df_kernel<<<NBH, 256, 0, stream>>>(pp, temperature, gate, dec, dfb);

  scan_phase1<<<NBH * NC, 256, 0, stream>>>(qkva, dec, dfb, gate, kvcs, zcs,
                                            Aarr, outp, zloc, pLoc);

  combine_kernel<<<390, 256, 0, stream>>>(Aarr, kvcs, zcs);

  scan_phase3<<<NBH * NC, 256, 0, stream>>>(qkva, kvcs, zcs, outp, zloc, pLoc,
                                            mn_g, mn_b, att_bf);

  gemm_mfma_kernel<64, 0, true, false><<<dim3(6, 32), 256, 0, stream>>>(
      att_bf, projw_bf, proj_b, y, nullptr, 2048, 768, 768);
}